// Round 8
// baseline (4486.495 us; speedup 1.0000x reference)
//
#include <hip/hip_runtime.h>
#include <math.h>

// MultiScaleCodebook on MI355X — round 8: revert conv to verified VALU math,
// fix its occupancy. r7 post-mortem: f64-MFMA conv wrong (w-permutation-class
// error = unverified f64 fragment layout; hidden by coarse pooling at scale 1,
// exposed at scale 2). r6 conv was correct but 1 block/CU (grid 256, 4
// waves/CU -> no LDS latency hiding, VALUBusy 34%). Fix: grid 512 (b,t,h),
// 2 blocks/CU, bit-identical per-element sum chain (ci0 -> tap -> cc).
// Keep r7's refine grid capping. bf16-MFMA argmin etc. unchanged from r6.

#define NCODES 16384
#define NELEM  524288   // 8*64*4*16*16
#define NSP    8192     // 8*4*16*16

#define WS_ACCU   0ul
#define WS_HUP    4194304ul
#define WS_REST64 8388608ul
#define WS_PART   12582912ul   // 2MB; refine pbest aliases this
#define WS_ZCL    16777216ul
#define WS_EHF    18874368ul   // emb bf16-hi frags, 2MB
#define WS_ELF    20971520ul   // emb bf16-lo frags, 2MB
#define WS_ESQ    23068672ul
#define WS_TWT    23134208ul
#define WS_IDX    24903680ul
#define WS_CNT    24936448ul
#define WS_FLAGL  25001984ul
#define WS_FLAGC  25034752ul
#define WS_SSE    25034816ul
#define WS_ENT    25034824ul
#define WS_USED   25034832ul
#define WS_RHF    25034848ul   // rest bf16-hi frags, 1MB
#define WS_RLF    26083424ul   // rest bf16-lo frags, 1MB

typedef __attribute__((ext_vector_type(8))) short short8;
typedef __attribute__((ext_vector_type(4))) float floatx4;

struct PBest { double d; int idx; int pad; };

// round-to-nearest-even float -> bf16; also returns hi as float
__device__ inline short bf16rne(float f, float* hi) {
  unsigned u = __float_as_uint(f);
  unsigned r = (u + 0x7FFFu + ((u >> 16) & 1u)) >> 16;
  *hi = __uint_as_float(r << 16);
  return (short)r;
}

// ---------------------------------------------------------------- prep
__global__ __launch_bounds__(256) void prep_kernel(
    const float* __restrict__ z, const float* __restrict__ emb, const float* __restrict__ Wq,
    double* __restrict__ accu, float* __restrict__ zcl,
    short* __restrict__ ehf, short* __restrict__ elf,
    float* __restrict__ esq, float* __restrict__ twt,
    int* __restrict__ counts, int* __restrict__ flagcnt,
    double* sse, double* ent, int* usedcnt)
{
  int i = blockIdx.x * 256 + threadIdx.x;
  if (i < NELEM) { accu[i] = 0.0; return; }
  i -= NELEM;
  if (i < NELEM) {  // z [B,C,T,H,W] -> zcl [B,T,H,W,C]
    int c = i & 63, w = (i >> 6) & 15, h = (i >> 10) & 15, t = (i >> 14) & 3, b = i >> 16;
    zcl[i] = z[(((b * 64 + c) * 4 + t) * 16 + h) * 16 + w];
    return;
  }
  i -= NELEM;
  if (i < NCODES * 64) {  // emb -> bf16 split, MFMA B-frag order
    int j = i >> 6, c = i & 63;
    float v = emb[i];
    float hi; short h = bf16rne(v, &hi);
    float hi2; short l = bf16rne(v - hi, &hi2);
    int jt = j >> 4, nn = j & 15, hf = c >> 5, q = (c >> 3) & 3, ii = c & 7;
    size_t slot = ((size_t)(((jt * 2 + hf) * 64) + q * 16 + nn)) * 8 + ii;
    ehf[slot] = h; elf[slot] = l;
    return;
  }
  i -= NCODES * 64;
  if (i < NCODES) {  // e_sq fp32 (ranking only; refine is fp64)
    float s = 0.f;
    for (int c = 0; c < 64; c++) { float v = emb[i * 64 + c]; s += v * v; }
    esq[i] = s; return;
  }
  i -= NCODES;
  if (i < 442368) {  // twt[qi][tap][ci][co] = Wq[qi][co][ci][tap]
    int qi = i / 110592; int r = i % 110592;
    int tap = r >> 12; int ci = (r >> 6) & 63; int co = r & 63;
    twt[i] = Wq[((qi * 64 + co) * 64 + ci) * 27 + tap];
    return;
  }
  i -= 442368;
  if (i < NCODES) { counts[i] = 0; return; }
  i -= NCODES;
  if (i < 16) {
    if (i < 10) flagcnt[i] = 0;
    else if (i == 10) *sse = 0.0;
    else if (i == 11) *ent = 0.0;
    else if (i == 12) *usedcnt = 0;
  }
}

// ------------------------------------------- pool (area) + frag emit
__global__ __launch_bounds__(256) void pool_kernel(
    const float* __restrict__ zcl, const double* __restrict__ accu,
    double* __restrict__ rest64, short* __restrict__ rhf, short* __restrict__ rlf,
    int N, int tpn, int pn)
{
  __shared__ double psum[4][64];
  int n = blockIdx.x;
  int tid = threadIdx.x;
  int c = tid & 63, ck = tid >> 6;
  if (n >= N) {  // zero pad rows so argmin frags are defined
    if (tid < 64) {
      int pt = n >> 4, m = n & 15, hf = tid >> 5, q = (tid >> 3) & 3, ii = tid & 7;
      size_t slot = ((size_t)(((pt * 2 + hf) * 64) + q * 16 + m)) * 8 + ii;
      rhf[slot] = 0; rlf[slot] = 0;
    }
    return;
  }
  int ppn = pn * pn;
  int b = n / (tpn * ppn); int r = n % (tpn * ppn);
  int u = r / ppn; r %= ppn; int v = r / pn; int x = r % pn;
  int t0 = (u * 4) / tpn, t1 = ((u + 1) * 4 + tpn - 1) / tpn;
  int h0 = (v * 16) / pn, h1 = ((v + 1) * 16 + pn - 1) / pn;
  int w0 = (x * 16) / pn, w1 = ((x + 1) * 16 + pn - 1) / pn;
  int nt = t1 - t0, nh = h1 - h0, nw = w1 - w0;
  int M = nt * nh * nw;
  int chunk = (M + 3) >> 2;
  int m0 = ck * chunk; int m1 = m0 + chunk; if (m1 > M) m1 = M;
  double s = 0.0;
  if (m0 < m1) {
    int tmp = m0 / nw; int wi = m0 - tmp * nw;
    int ti = tmp / nh; int hi = tmp - ti * nh;
    for (int m = m0; m < m1; m++) {
      size_t off = (size_t)((((b * 4 + t0 + ti) * 16 + h0 + hi) * 16 + w0 + wi) * 64 + c);
      s += (double)zcl[off] - accu[off];
      if (++wi == nw) { wi = 0; if (++hi == nh) { hi = 0; ++ti; } }
    }
  }
  psum[ck][c] = s;
  __syncthreads();
  if (tid < 64) {
    double t = ((psum[0][c] + psum[1][c]) + psum[2][c]) + psum[3][c];
    float wt = 1.f / (float)nt, wh = 1.f / (float)nh, ww = 1.f / (float)nw;
    double rv = t * (double)wt * (double)wh * (double)ww;
    rest64[(size_t)n * 64 + c] = rv;
    float rv32 = (float)rv;
    float hi; short h = bf16rne(rv32, &hi);
    float hi2; short l = bf16rne(rv32 - hi, &hi2);
    int pt = n >> 4, m = n & 15, hf = c >> 5, q = (c >> 3) & 3, ii = c & 7;
    size_t slot = ((size_t)(((pt * 2 + hf) * 64) + q * 16 + m)) * 8 + ii;
    rhf[slot] = h; rlf[slot] = l;
  }
}

// ------------------------------------------- argmin pass 1 (bf16 MFMA GEMM)
__global__ __launch_bounds__(256) void argmin_kernel(
    const short* __restrict__ rhf, const short* __restrict__ rlf,
    const short* __restrict__ ehf, const short* __restrict__ elf,
    const float* __restrict__ esq, float4* __restrict__ part)
{
  __shared__ short8 Ah[4][2][64];
  __shared__ short8 Al[4][2][64];
  __shared__ short8 Bh[8][2][64];
  __shared__ short8 Bl[8][2][64];
  __shared__ float esql[128];
  int tid = threadIdx.x;
  int pbase = blockIdx.x * 64;
  int ch = blockIdx.y;
  {
    const short8* sH = (const short8*)(rhf + (size_t)pbase * 64);
    const short8* sL = (const short8*)(rlf + (size_t)pbase * 64);
    short8* dH = (short8*)Ah; short8* dL = (short8*)Al;
    dH[tid] = sH[tid]; dH[tid + 256] = sH[tid + 256];
    dL[tid] = sL[tid]; dL[tid + 256] = sL[tid + 256];
  }
  __syncthreads();
  int w = tid >> 6, lane = tid & 63, col = lane & 15;
  short8 ah0 = Ah[w][0][lane], ah1 = Ah[w][1][lane];
  short8 al0 = Al[w][0][lane], al1 = Al[w][1][lane];
  float m1[4], m2[4]; int i1[4];
#pragma unroll
  for (int r = 0; r < 4; r++) { m1[r] = 3.4e38f; m2[r] = 3.4e38f; i1[r] = 0x7fffffff; }
  for (int s = 0; s < 8; s++) {
    int j0 = ch * 1024 + s * 128;
    __syncthreads();
    {
      const short8* sH = (const short8*)(ehf + (size_t)j0 * 64);
      const short8* sL = (const short8*)(elf + (size_t)j0 * 64);
      short8* dH = (short8*)Bh; short8* dL = (short8*)Bl;
#pragma unroll
      for (int it = 0; it < 4; it++) { dH[tid + it * 256] = sH[tid + it * 256]; dL[tid + it * 256] = sL[tid + it * 256]; }
      if (tid < 128) esql[tid] = esq[j0 + tid];
    }
    __syncthreads();
    floatx4 acc[8];
#pragma unroll
    for (int jt = 0; jt < 8; jt++) acc[jt] = (floatx4){0.f, 0.f, 0.f, 0.f};
#pragma unroll
    for (int jt = 0; jt < 8; jt++) {
      short8 bh0 = Bh[jt][0][lane], bl0 = Bl[jt][0][lane];
      short8 bh1 = Bh[jt][1][lane], bl1 = Bl[jt][1][lane];
      acc[jt] = __builtin_amdgcn_mfma_f32_16x16x32_bf16(al0, bh0, acc[jt], 0, 0, 0);
      acc[jt] = __builtin_amdgcn_mfma_f32_16x16x32_bf16(ah0, bl0, acc[jt], 0, 0, 0);
      acc[jt] = __builtin_amdgcn_mfma_f32_16x16x32_bf16(ah0, bh0, acc[jt], 0, 0, 0);
      acc[jt] = __builtin_amdgcn_mfma_f32_16x16x32_bf16(al1, bh1, acc[jt], 0, 0, 0);
      acc[jt] = __builtin_amdgcn_mfma_f32_16x16x32_bf16(ah1, bl1, acc[jt], 0, 0, 0);
      acc[jt] = __builtin_amdgcn_mfma_f32_16x16x32_bf16(ah1, bh1, acc[jt], 0, 0, 0);
    }
#pragma unroll
    for (int jt = 0; jt < 8; jt++) {
      float es = esql[jt * 16 + col];
      int j = j0 + jt * 16 + col;
#pragma unroll
      for (int r = 0; r < 4; r++) {
        float d = fmaf(-2.f, acc[jt][r], es);
        if (d < m1[r]) { m2[r] = m1[r]; m1[r] = d; i1[r] = j; }
        else if (d < m2[r]) { m2[r] = d; }
      }
    }
  }
#pragma unroll
  for (int off = 1; off < 16; off <<= 1) {
#pragma unroll
    for (int r = 0; r < 4; r++) {
      float o1 = __shfl_xor(m1[r], off);
      int   oi = __shfl_xor(i1[r], off);
      float o2 = __shfl_xor(m2[r], off);
      bool bwin = (o1 < m1[r]) || (o1 == m1[r] && oi < i1[r]);
      float nm2 = bwin ? fminf(m1[r], o2) : fminf(m2[r], o1);
      if (bwin) { m1[r] = o1; i1[r] = oi; }
      m2[r] = nm2;
    }
  }
  if (col == 0) {
    int quad = lane >> 4;
#pragma unroll
    for (int r = 0; r < 4; r++) {
      int p = pbase + w * 16 + quad * 4 + r;
      part[(size_t)ch * NSP + p] = make_float4(m1[r], m2[r], __int_as_float(i1[r]), 0.f);
    }
  }
}

// ---------------------------- merge chunks, flag near-ties to global list
__global__ __launch_bounds__(256) void reduce_kernel(
    const float4* __restrict__ part, int* __restrict__ idx_cur,
    float* __restrict__ out_idx, int* flagcnt, int* flaglist, int N)
{
  int n = blockIdx.x * 256 + threadIdx.x;
  if (n >= N) return;
  float m1 = 3.4e38f, m2 = 3.4e38f; int i1 = 0x7fffffff;
  for (int ch = 0; ch < 16; ch++) {
    float4 q = part[(size_t)ch * NSP + n];
    float o1 = q.x, o2 = q.y; int oi = __float_as_int(q.z);
    bool bwin = (o1 < m1) || (o1 == m1 && oi < i1);
    float nm2 = bwin ? fminf(m1, o2) : fminf(m2, o1);
    if (bwin) { m1 = o1; i1 = oi; }
    m2 = nm2;
  }
  idx_cur[n] = i1;
  out_idx[n] = (float)i1;
  if (m2 - m1 < 0.01f) {
    int pos = atomicAdd(flagcnt, 1);
    flaglist[pos] = n;
  }
}

// -------------------- parallel fp64 rescan: block = (flag-stride, 4096 chunk)
__global__ __launch_bounds__(256) void refine_kernel(
    const double* __restrict__ rest64, const float* __restrict__ emb,
    const int* __restrict__ flagcnt, const int* __restrict__ flaglist,
    PBest* __restrict__ pbest)
{
  __shared__ double rl[64];
  __shared__ double bm[256];
  __shared__ int    bi[256];
  int cnt = *flagcnt;
  int ch = blockIdx.y;
  int tid = threadIdx.x;
  for (int f = blockIdx.x; f < cnt; f += gridDim.x) {
    int n = flaglist[f];
    __syncthreads();
    if (tid < 64) rl[tid] = rest64[(size_t)n * 64 + tid];
    __syncthreads();
    double best = 1e300; int bidx = 0x7fffffff;
    for (int k = 0; k < 16; k++) {
      int j = ch * 4096 + k * 256 + tid;
      double d = 0.0;
      for (int c = 0; c < 64; c++) { double df = rl[c] - (double)emb[(size_t)j * 64 + c]; d += df * df; }
      if (d < best) { best = d; bidx = j; }
    }
    bm[tid] = best; bi[tid] = bidx;
    __syncthreads();
    for (int s = 128; s > 0; s >>= 1) {
      if (tid < s) {
        double ob = bm[tid + s]; int oi = bi[tid + s];
        if (ob < bm[tid] || (ob == bm[tid] && oi < bi[tid])) { bm[tid] = ob; bi[tid] = oi; }
      }
      __syncthreads();
    }
    if (tid == 0) { pbest[f * 4 + ch].d = bm[0]; pbest[f * 4 + ch].idx = bi[0]; }
  }
}

// -------------------------------- fold 4 chunk results per flagged point
__global__ __launch_bounds__(256) void refine_merge_kernel(
    const PBest* __restrict__ pbest, const int* __restrict__ flagcnt,
    const int* __restrict__ flaglist, int* __restrict__ idx_cur,
    float* __restrict__ out_idx)
{
  int f = blockIdx.x * 256 + threadIdx.x;
  if (f >= *flagcnt) return;
  double best = 1e300; int bidx = 0x7fffffff;
  for (int ch = 0; ch < 4; ch++) {
    double d = pbest[f * 4 + ch].d; int j = pbest[f * 4 + ch].idx;
    if (d < best || (d == best && j < bidx)) { best = d; bidx = j; }
  }
  int n = flaglist[f];
  idx_cur[n] = bidx;
  out_idx[n] = (float)bidx;
}

// ------------------------------------------------------- trilinear upsample
__device__ inline void axis_map(int L, int outlen, int i, int* j0, int* j1, float* a0, float* a1) {
  if (L == 1) { *j0 = 0; *j1 = 0; *a0 = 1.f; *a1 = 0.f; return; }
  double scale = (double)L / (double)outlen;
  double src = (i + 0.5) * scale - 0.5;
  if (src < 0.0) src = 0.0;
  int i0 = (int)floor(src); if (i0 > L - 1) i0 = L - 1;
  int i1 = i0 + 1; if (i1 > L - 1) i1 = L - 1;
  double wv = src - (double)i0;
  if (i0 == i1) {
    float p = (float)(1.0 - wv), q = (float)wv;
    *a0 = p + q; *a1 = 0.f;
  } else { *a0 = (float)(1.0 - wv); *a1 = (float)wv; }
  *j0 = i0; *j1 = i1;
}

__global__ __launch_bounds__(256) void upsample_kernel(
    const float* __restrict__ emb, const int* __restrict__ idx_cur,
    double* __restrict__ hup, int tpn, int pn)
{
  int e = blockIdx.x * 256 + threadIdx.x;
  int c = e & 63, w = (e >> 6) & 15, h = (e >> 10) & 15, t = (e >> 14) & 3, b = e >> 16;
  int t0, t1, h0, h1, w0, w1; float ta0, ta1, ha0, ha1, wa0, wa1;
  axis_map(tpn, 4, t, &t0, &t1, &ta0, &ta1);
  axis_map(pn, 16, h, &h0, &h1, &ha0, &ha1);
  axis_map(pn, 16, w, &w0, &w1, &wa0, &wa1);
  int ti[2] = {t0, t1}; float ta[2] = {ta0, ta1};
  int hi[2] = {h0, h1}; float ha[2] = {ha0, ha1};
  int wi[2] = {w0, w1}; float wa[2] = {wa0, wa1};
  double val = 0.0;
  for (int a = 0; a < 2; a++)
    for (int bb = 0; bb < 2; bb++)
      for (int cc = 0; cc < 2; cc++) {
        double wgt = (double)ta[a] * (double)ha[bb] * (double)wa[cc];
        if (wgt != 0.0) {
          int code = idx_cur[((b * tpn + ti[a]) * pn + hi[bb]) * pn + wi[cc]];
          val += wgt * (double)emb[(size_t)code * 64 + c];
        }
      }
  hup[e] = val;
}

// ------------------------------------------- conv3d + accu update + commit
// grid 512 = b*64 + t*16 + h ; block 256 = 16w x 16co4 ; 1 h-row/thread.
// Per-output-element sum chain (ci0 -> tap -> cc) bit-identical to r6's
// verified kernel; only the grid partitioning changed (2 blocks/CU).
__global__ __launch_bounds__(256) void conv_kernel(
    const double* __restrict__ hup, const float* __restrict__ twt, const float* __restrict__ bq,
    const float* __restrict__ zcl, double* __restrict__ accu, double* sse, int qi)
{
  __shared__ double hl[3][3][4][18];              // [tt][hh][cc][ww] halo, ci-chunk 4
  __shared__ __align__(16) float wl[27][4][64];   // [tap][cc][co] fp32 (exact)
  int bid = blockIdx.x;
  int b = bid >> 6, t = (bid >> 4) & 3, h = bid & 15;
  int tid = threadIdx.x;
  int co4 = tid >> 4;  // co = co4*4 .. +3
  int w = tid & 15;
  double acc[4] = {0.0, 0.0, 0.0, 0.0};
  for (int ci0 = 0; ci0 < 64; ci0 += 4) {
    __syncthreads();
    for (int i = tid; i < 648; i += 256) {
      int ww = i % 18; int r = i / 18; int cc = r & 3; r >>= 2; int hh = r % 3; int tt = r / 3;
      int gt = t - 1 + tt, gh = h - 1 + hh, gw = ww - 1;
      double v = 0.0;
      if (gt >= 0 && gt < 4 && gh >= 0 && gh < 16 && gw >= 0 && gw < 16)
        v = hup[(size_t)((((b * 4 + gt) * 16 + gh) * 16 + gw) * 64 + ci0 + cc)];
      hl[tt][hh][cc][ww] = v;
    }
    for (int i = tid; i < 6912; i += 256) {
      int co = i & 63; int r = i >> 6; int cc = r & 3; int tap = r >> 2;
      wl[tap][cc][co] = twt[(size_t)(((qi * 27 + tap) * 64 + ci0 + cc) * 64 + co)];
    }
    __syncthreads();
    for (int tap = 0; tap < 27; tap++) {
      int dt = tap / 9, dh = (tap / 3) % 3, dw = tap % 3;
#pragma unroll
      for (int cc = 0; cc < 4; cc++) {
        float4 wf = *(const float4*)&wl[tap][cc][co4 * 4];
        double hv = hl[dt][dh][cc][w + dw];
        acc[0] += hv * (double)wf.x; acc[1] += hv * (double)wf.y;
        acc[2] += hv * (double)wf.z; acc[3] += hv * (double)wf.w;
      }
    }
  }
  double lsse = 0.0;
#pragma unroll
  for (int q = 0; q < 4; q++) {
    int co = co4 * 4 + q;
    size_t off = (size_t)((((b * 4 + t) * 16 + h) * 16 + w) * 64 + co);
    double conv = acc[q] + (double)bq[qi * 64 + co];
    double hu = hup[off];
    double na = accu[off] + 0.5 * hu + 0.5 * conv;  // h*(1-q) + conv*q, q=0.5
    accu[off] = na;
    double df = na - (double)zcl[off];
    lsse += df * df;
  }
#pragma unroll
  for (int o = 32; o > 0; o >>= 1) lsse += __shfl_down(lsse, o);
  if ((tid & 63) == 0) atomicAdd(sse, lsse);
}

// ---------------------------------------------------------------- stats
__global__ __launch_bounds__(256) void bincount_kernel(const int* __restrict__ idx_cur, int* counts) {
  int i = blockIdx.x * 256 + threadIdx.x;
  if (i < NSP) atomicAdd(&counts[idx_cur[i]], 1);
}

__global__ __launch_bounds__(256) void stats_kernel(
    const int* __restrict__ counts, float* __restrict__ usage_out, double* ent, int* usedcnt)
{
  __shared__ double re[256];
  __shared__ int ru[256];
  int j = blockIdx.x * 256 + threadIdx.x;
  int cnt = counts[j];
  double p = (double)cnt / 8192.0;
  usage_out[j] = (float)p;
  re[threadIdx.x] = p * log(p + 1e-10);
  ru[threadIdx.x] = cnt > 0 ? 1 : 0;
  __syncthreads();
  for (int s = 128; s > 0; s >>= 1) {
    if (threadIdx.x < s) { re[threadIdx.x] += re[threadIdx.x + s]; ru[threadIdx.x] += ru[threadIdx.x + s]; }
    __syncthreads();
  }
  if (threadIdx.x == 0) { atomicAdd(ent, re[0]); atomicAdd(usedcnt, ru[0]); }
}

__global__ void final_kernel(const double* sse, const double* ent, const int* usedcnt, float* out) {
  if (threadIdx.x == 0) {
    out[NELEM]     = (float)(*sse * 0.25 / 524288.0 / 10.0);
    out[NELEM + 1] = (float)exp(-*ent);
    out[NELEM + 2] = (float)((double)*usedcnt / 16384.0);
  }
}

__global__ __launch_bounds__(256) void embst_kernel(const double* __restrict__ accu, float* __restrict__ out) {
  int e = blockIdx.x * 256 + threadIdx.x;
  int w = e & 15, h = (e >> 4) & 15, t = (e >> 8) & 3, c = (e >> 10) & 63, b = e >> 16;
  out[e] = (float)accu[(size_t)(((((b * 4 + t) * 16 + h) * 16 + w) * 64) + c)];
}

// ---------------------------------------------------------------- launch
extern "C" void kernel_launch(void* const* d_in, const int* in_sizes, int n_in,
                              void* d_out, int out_size, void* d_ws, size_t ws_size,
                              hipStream_t stream) {
  static const int T_PN_h[10] = {1, 1, 2, 2, 2, 4, 4, 4, 4, 4};
  static const int V_PN_h[10] = {1, 2, 3, 4, 5, 6, 8, 10, 13, 16};
  // qi from bit-exact fp64 emulation of np.linspace+argmin (ties: si=2->1, si=7->3)
  static const int QI_h[10]   = {0, 0, 1, 1, 1, 2, 2, 3, 3, 3};
  static const int NS_h[10]   = {8, 32, 144, 256, 400, 1152, 2048, 3200, 5408, 8192};
  static const int OB_h[10]   = {540675, 540683, 540715, 540859, 541115,
                                 541515, 542667, 544715, 547915, 553323};

  const float* z   = (const float*)d_in[0];
  const float* emb = (const float*)d_in[1];
  const float* Wq  = (const float*)d_in[2];
  const float* bq  = (const float*)d_in[3];
  float* out = (float*)d_out;
  char* ws = (char*)d_ws;

  double* accu    = (double*)(ws + WS_ACCU);
  double* hup     = (double*)(ws + WS_HUP);
  double* rest64  = (double*)(ws + WS_REST64);
  float4* part    = (float4*)(ws + WS_PART);
  PBest*  pbest   = (PBest*)(ws + WS_PART);
  float*  zcl     = (float*)(ws + WS_ZCL);
  short*  ehf     = (short*)(ws + WS_EHF);
  short*  elf     = (short*)(ws + WS_ELF);
  float*  esq     = (float*)(ws + WS_ESQ);
  float*  twt     = (float*)(ws + WS_TWT);
  int*    idx_cur = (int*)(ws + WS_IDX);
  int*    counts  = (int*)(ws + WS_CNT);
  int*    flaglist= (int*)(ws + WS_FLAGL);
  int*    flagcnt = (int*)(ws + WS_FLAGC);
  double* sse     = (double*)(ws + WS_SSE);
  double* ent     = (double*)(ws + WS_ENT);
  int*    usedcnt = (int*)(ws + WS_USED);
  short*  rhf     = (short*)(ws + WS_RHF);
  short*  rlf     = (short*)(ws + WS_RLF);

  prep_kernel<<<10049, 256, 0, stream>>>(z, emb, Wq, accu, zcl, ehf, elf, esq, twt,
                                         counts, flagcnt, sse, ent, usedcnt);

  for (int si = 0; si < 10; si++) {
    int tpn = T_PN_h[si], pn = V_PN_h[si], N = NS_h[si];
    int NSpad = (N + 63) & ~63;
    pool_kernel<<<NSpad, 256, 0, stream>>>(zcl, accu, rest64, rhf, rlf, N, tpn, pn);
    dim3 ag(NSpad / 64, 16);
    argmin_kernel<<<ag, 256, 0, stream>>>(rhf, rlf, ehf, elf, esq, part);
    reduce_kernel<<<(N + 255) / 256, 256, 0, stream>>>(part, idx_cur, out + OB_h[si],
                                                       flagcnt + si, flaglist, N);
    int rgx = N < 1024 ? N : 1024;
    dim3 rg(rgx, 4);
    refine_kernel<<<rg, 256, 0, stream>>>(rest64, emb, flagcnt + si, flaglist, pbest);
    refine_merge_kernel<<<(N + 255) / 256, 256, 0, stream>>>(pbest, flagcnt + si, flaglist,
                                                             idx_cur, out + OB_h[si]);
    upsample_kernel<<<NELEM / 256, 256, 0, stream>>>(emb, idx_cur, hup, tpn, pn);
    conv_kernel<<<512, 256, 0, stream>>>(hup, twt, bq, zcl, accu, sse, QI_h[si]);
  }

  bincount_kernel<<<32, 256, 0, stream>>>(idx_cur, counts);
  stats_kernel<<<64, 256, 0, stream>>>(counts, out + 524291, ent, usedcnt);
  final_kernel<<<1, 64, 0, stream>>>(sse, ent, usedcnt, out);
  embst_kernel<<<NELEM / 256, 256, 0, stream>>>(accu, out);
}

// Round 9
// 2522.036 us; speedup vs baseline: 1.7789x; 1.7789x over previous
//
#include <hip/hip_runtime.h>
#include <math.h>

// MultiScaleCodebook on MI355X — round 9: un-spill refine.
// r8 post-mortem: r7's grid-stride f-loop in refine made the compiler unroll
// the 16x64 FMA chain past 256 VGPRs -> scratch spill (WRITE_SIZE 225MB,
// 440us x10 = the regression). Fix: back to r6's early-exit one-flag-per-
// block structure + #pragma unroll 1 on the chunk loop + float4 codebook
// loads (same ascending-c fp64 sum order -> bit-identical). Conv grid 512
// (r8, verified) and bf16-MFMA argmin (r6) unchanged.

#define NCODES 16384
#define NELEM  524288   // 8*64*4*16*16
#define NSP    8192     // 8*4*16*16

#define WS_ACCU   0ul
#define WS_HUP    4194304ul
#define WS_REST64 8388608ul
#define WS_PART   12582912ul   // 2MB; refine pbest aliases this
#define WS_ZCL    16777216ul
#define WS_EHF    18874368ul   // emb bf16-hi frags, 2MB
#define WS_ELF    20971520ul   // emb bf16-lo frags, 2MB
#define WS_ESQ    23068672ul
#define WS_TWT    23134208ul
#define WS_IDX    24903680ul
#define WS_CNT    24936448ul
#define WS_FLAGL  25001984ul
#define WS_FLAGC  25034752ul
#define WS_SSE    25034816ul
#define WS_ENT    25034824ul
#define WS_USED   25034832ul
#define WS_RHF    25034848ul   // rest bf16-hi frags, 1MB
#define WS_RLF    26083424ul   // rest bf16-lo frags, 1MB

typedef __attribute__((ext_vector_type(8))) short short8;
typedef __attribute__((ext_vector_type(4))) float floatx4;

struct PBest { double d; int idx; int pad; };

// round-to-nearest-even float -> bf16; also returns hi as float
__device__ inline short bf16rne(float f, float* hi) {
  unsigned u = __float_as_uint(f);
  unsigned r = (u + 0x7FFFu + ((u >> 16) & 1u)) >> 16;
  *hi = __uint_as_float(r << 16);
  return (short)r;
}

// ---------------------------------------------------------------- prep
__global__ __launch_bounds__(256) void prep_kernel(
    const float* __restrict__ z, const float* __restrict__ emb, const float* __restrict__ Wq,
    double* __restrict__ accu, float* __restrict__ zcl,
    short* __restrict__ ehf, short* __restrict__ elf,
    float* __restrict__ esq, float* __restrict__ twt,
    int* __restrict__ counts, int* __restrict__ flagcnt,
    double* sse, double* ent, int* usedcnt)
{
  int i = blockIdx.x * 256 + threadIdx.x;
  if (i < NELEM) { accu[i] = 0.0; return; }
  i -= NELEM;
  if (i < NELEM) {  // z [B,C,T,H,W] -> zcl [B,T,H,W,C]
    int c = i & 63, w = (i >> 6) & 15, h = (i >> 10) & 15, t = (i >> 14) & 3, b = i >> 16;
    zcl[i] = z[(((b * 64 + c) * 4 + t) * 16 + h) * 16 + w];
    return;
  }
  i -= NELEM;
  if (i < NCODES * 64) {  // emb -> bf16 split, MFMA B-frag order
    int j = i >> 6, c = i & 63;
    float v = emb[i];
    float hi; short h = bf16rne(v, &hi);
    float hi2; short l = bf16rne(v - hi, &hi2);
    int jt = j >> 4, nn = j & 15, hf = c >> 5, q = (c >> 3) & 3, ii = c & 7;
    size_t slot = ((size_t)(((jt * 2 + hf) * 64) + q * 16 + nn)) * 8 + ii;
    ehf[slot] = h; elf[slot] = l;
    return;
  }
  i -= NCODES * 64;
  if (i < NCODES) {  // e_sq fp32 (ranking only; refine is fp64)
    float s = 0.f;
    for (int c = 0; c < 64; c++) { float v = emb[i * 64 + c]; s += v * v; }
    esq[i] = s; return;
  }
  i -= NCODES;
  if (i < 442368) {  // twt[qi][tap][ci][co] = Wq[qi][co][ci][tap]
    int qi = i / 110592; int r = i % 110592;
    int tap = r >> 12; int ci = (r >> 6) & 63; int co = r & 63;
    twt[i] = Wq[((qi * 64 + co) * 64 + ci) * 27 + tap];
    return;
  }
  i -= 442368;
  if (i < NCODES) { counts[i] = 0; return; }
  i -= NCODES;
  if (i < 16) {
    if (i < 10) flagcnt[i] = 0;
    else if (i == 10) *sse = 0.0;
    else if (i == 11) *ent = 0.0;
    else if (i == 12) *usedcnt = 0;
  }
}

// ------------------------------------------- pool (area) + frag emit
__global__ __launch_bounds__(256) void pool_kernel(
    const float* __restrict__ zcl, const double* __restrict__ accu,
    double* __restrict__ rest64, short* __restrict__ rhf, short* __restrict__ rlf,
    int N, int tpn, int pn)
{
  __shared__ double psum[4][64];
  int n = blockIdx.x;
  int tid = threadIdx.x;
  int c = tid & 63, ck = tid >> 6;
  if (n >= N) {  // zero pad rows so argmin frags are defined
    if (tid < 64) {
      int pt = n >> 4, m = n & 15, hf = tid >> 5, q = (tid >> 3) & 3, ii = tid & 7;
      size_t slot = ((size_t)(((pt * 2 + hf) * 64) + q * 16 + m)) * 8 + ii;
      rhf[slot] = 0; rlf[slot] = 0;
    }
    return;
  }
  int ppn = pn * pn;
  int b = n / (tpn * ppn); int r = n % (tpn * ppn);
  int u = r / ppn; r %= ppn; int v = r / pn; int x = r % pn;
  int t0 = (u * 4) / tpn, t1 = ((u + 1) * 4 + tpn - 1) / tpn;
  int h0 = (v * 16) / pn, h1 = ((v + 1) * 16 + pn - 1) / pn;
  int w0 = (x * 16) / pn, w1 = ((x + 1) * 16 + pn - 1) / pn;
  int nt = t1 - t0, nh = h1 - h0, nw = w1 - w0;
  int M = nt * nh * nw;
  int chunk = (M + 3) >> 2;
  int m0 = ck * chunk; int m1 = m0 + chunk; if (m1 > M) m1 = M;
  double s = 0.0;
  if (m0 < m1) {
    int tmp = m0 / nw; int wi = m0 - tmp * nw;
    int ti = tmp / nh; int hi = tmp - ti * nh;
    for (int m = m0; m < m1; m++) {
      size_t off = (size_t)((((b * 4 + t0 + ti) * 16 + h0 + hi) * 16 + w0 + wi) * 64 + c);
      s += (double)zcl[off] - accu[off];
      if (++wi == nw) { wi = 0; if (++hi == nh) { hi = 0; ++ti; } }
    }
  }
  psum[ck][c] = s;
  __syncthreads();
  if (tid < 64) {
    double t = ((psum[0][c] + psum[1][c]) + psum[2][c]) + psum[3][c];
    float wt = 1.f / (float)nt, wh = 1.f / (float)nh, ww = 1.f / (float)nw;
    double rv = t * (double)wt * (double)wh * (double)ww;
    rest64[(size_t)n * 64 + c] = rv;
    float rv32 = (float)rv;
    float hi; short h = bf16rne(rv32, &hi);
    float hi2; short l = bf16rne(rv32 - hi, &hi2);
    int pt = n >> 4, m = n & 15, hf = c >> 5, q = (c >> 3) & 3, ii = c & 7;
    size_t slot = ((size_t)(((pt * 2 + hf) * 64) + q * 16 + m)) * 8 + ii;
    rhf[slot] = h; rlf[slot] = l;
  }
}

// ------------------------------------------- argmin pass 1 (bf16 MFMA GEMM)
__global__ __launch_bounds__(256) void argmin_kernel(
    const short* __restrict__ rhf, const short* __restrict__ rlf,
    const short* __restrict__ ehf, const short* __restrict__ elf,
    const float* __restrict__ esq, float4* __restrict__ part)
{
  __shared__ short8 Ah[4][2][64];
  __shared__ short8 Al[4][2][64];
  __shared__ short8 Bh[8][2][64];
  __shared__ short8 Bl[8][2][64];
  __shared__ float esql[128];
  int tid = threadIdx.x;
  int pbase = blockIdx.x * 64;
  int ch = blockIdx.y;
  {
    const short8* sH = (const short8*)(rhf + (size_t)pbase * 64);
    const short8* sL = (const short8*)(rlf + (size_t)pbase * 64);
    short8* dH = (short8*)Ah; short8* dL = (short8*)Al;
    dH[tid] = sH[tid]; dH[tid + 256] = sH[tid + 256];
    dL[tid] = sL[tid]; dL[tid + 256] = sL[tid + 256];
  }
  __syncthreads();
  int w = tid >> 6, lane = tid & 63, col = lane & 15;
  short8 ah0 = Ah[w][0][lane], ah1 = Ah[w][1][lane];
  short8 al0 = Al[w][0][lane], al1 = Al[w][1][lane];
  float m1[4], m2[4]; int i1[4];
#pragma unroll
  for (int r = 0; r < 4; r++) { m1[r] = 3.4e38f; m2[r] = 3.4e38f; i1[r] = 0x7fffffff; }
  for (int s = 0; s < 8; s++) {
    int j0 = ch * 1024 + s * 128;
    __syncthreads();
    {
      const short8* sH = (const short8*)(ehf + (size_t)j0 * 64);
      const short8* sL = (const short8*)(elf + (size_t)j0 * 64);
      short8* dH = (short8*)Bh; short8* dL = (short8*)Bl;
#pragma unroll
      for (int it = 0; it < 4; it++) { dH[tid + it * 256] = sH[tid + it * 256]; dL[tid + it * 256] = sL[tid + it * 256]; }
      if (tid < 128) esql[tid] = esq[j0 + tid];
    }
    __syncthreads();
    floatx4 acc[8];
#pragma unroll
    for (int jt = 0; jt < 8; jt++) acc[jt] = (floatx4){0.f, 0.f, 0.f, 0.f};
#pragma unroll
    for (int jt = 0; jt < 8; jt++) {
      short8 bh0 = Bh[jt][0][lane], bl0 = Bl[jt][0][lane];
      short8 bh1 = Bh[jt][1][lane], bl1 = Bl[jt][1][lane];
      acc[jt] = __builtin_amdgcn_mfma_f32_16x16x32_bf16(al0, bh0, acc[jt], 0, 0, 0);
      acc[jt] = __builtin_amdgcn_mfma_f32_16x16x32_bf16(ah0, bl0, acc[jt], 0, 0, 0);
      acc[jt] = __builtin_amdgcn_mfma_f32_16x16x32_bf16(ah0, bh0, acc[jt], 0, 0, 0);
      acc[jt] = __builtin_amdgcn_mfma_f32_16x16x32_bf16(al1, bh1, acc[jt], 0, 0, 0);
      acc[jt] = __builtin_amdgcn_mfma_f32_16x16x32_bf16(ah1, bl1, acc[jt], 0, 0, 0);
      acc[jt] = __builtin_amdgcn_mfma_f32_16x16x32_bf16(ah1, bh1, acc[jt], 0, 0, 0);
    }
#pragma unroll
    for (int jt = 0; jt < 8; jt++) {
      float es = esql[jt * 16 + col];
      int j = j0 + jt * 16 + col;
#pragma unroll
      for (int r = 0; r < 4; r++) {
        float d = fmaf(-2.f, acc[jt][r], es);
        if (d < m1[r]) { m2[r] = m1[r]; m1[r] = d; i1[r] = j; }
        else if (d < m2[r]) { m2[r] = d; }
      }
    }
  }
#pragma unroll
  for (int off = 1; off < 16; off <<= 1) {
#pragma unroll
    for (int r = 0; r < 4; r++) {
      float o1 = __shfl_xor(m1[r], off);
      int   oi = __shfl_xor(i1[r], off);
      float o2 = __shfl_xor(m2[r], off);
      bool bwin = (o1 < m1[r]) || (o1 == m1[r] && oi < i1[r]);
      float nm2 = bwin ? fminf(m1[r], o2) : fminf(m2[r], o1);
      if (bwin) { m1[r] = o1; i1[r] = oi; }
      m2[r] = nm2;
    }
  }
  if (col == 0) {
    int quad = lane >> 4;
#pragma unroll
    for (int r = 0; r < 4; r++) {
      int p = pbase + w * 16 + quad * 4 + r;
      part[(size_t)ch * NSP + p] = make_float4(m1[r], m2[r], __int_as_float(i1[r]), 0.f);
    }
  }
}

// ---------------------------- merge chunks, flag near-ties to global list
__global__ __launch_bounds__(256) void reduce_kernel(
    const float4* __restrict__ part, int* __restrict__ idx_cur,
    float* __restrict__ out_idx, int* flagcnt, int* flaglist, int N)
{
  int n = blockIdx.x * 256 + threadIdx.x;
  if (n >= N) return;
  float m1 = 3.4e38f, m2 = 3.4e38f; int i1 = 0x7fffffff;
  for (int ch = 0; ch < 16; ch++) {
    float4 q = part[(size_t)ch * NSP + n];
    float o1 = q.x, o2 = q.y; int oi = __float_as_int(q.z);
    bool bwin = (o1 < m1) || (o1 == m1 && oi < i1);
    float nm2 = bwin ? fminf(m1, o2) : fminf(m2, o1);
    if (bwin) { m1 = o1; i1 = oi; }
    m2 = nm2;
  }
  idx_cur[n] = i1;
  out_idx[n] = (float)i1;
  if (m2 - m1 < 0.01f) {
    int pos = atomicAdd(flagcnt, 1);
    flaglist[pos] = n;
  }
}

// -------------------- parallel fp64 rescan: block = (flag, 4096-code chunk)
// One flag per block (early exit) — r6 structure; unroll 1 + float4 loads
// keep VGPRs low (r8's f-loop version spilled at 256 VGPR, 225MB scratch).
__global__ __launch_bounds__(256) void refine_kernel(
    const double* __restrict__ rest64, const float* __restrict__ emb,
    const int* __restrict__ flagcnt, const int* __restrict__ flaglist,
    PBest* __restrict__ pbest)
{
  __shared__ double rl[64];
  __shared__ double bm[256];
  __shared__ int    bi[256];
  int f = blockIdx.x;
  if (f >= *flagcnt) return;
  int ch = blockIdx.y;
  int tid = threadIdx.x;
  int n = flaglist[f];
  if (tid < 64) rl[tid] = rest64[(size_t)n * 64 + tid];
  __syncthreads();
  double best = 1e300; int bidx = 0x7fffffff;
#pragma unroll 1
  for (int k = 0; k < 16; k++) {
    int j = ch * 4096 + k * 256 + tid;
    double d = 0.0;
    const float4* ej = (const float4*)&emb[(size_t)j * 64];
#pragma unroll
    for (int c4 = 0; c4 < 16; c4++) {
      float4 ev = ej[c4];
      double d0 = rl[c4 * 4 + 0] - (double)ev.x;
      double d1 = rl[c4 * 4 + 1] - (double)ev.y;
      double d2 = rl[c4 * 4 + 2] - (double)ev.z;
      double d3 = rl[c4 * 4 + 3] - (double)ev.w;
      d += d0 * d0; d += d1 * d1; d += d2 * d2; d += d3 * d3;
    }
    if (d < best) { best = d; bidx = j; }  // ascending j keeps first min
  }
  bm[tid] = best; bi[tid] = bidx;
  __syncthreads();
  for (int s = 128; s > 0; s >>= 1) {
    if (tid < s) {
      double ob = bm[tid + s]; int oi = bi[tid + s];
      if (ob < bm[tid] || (ob == bm[tid] && oi < bi[tid])) { bm[tid] = ob; bi[tid] = oi; }
    }
    __syncthreads();
  }
  if (tid == 0) { pbest[f * 4 + ch].d = bm[0]; pbest[f * 4 + ch].idx = bi[0]; }
}

// -------------------------------- fold 4 chunk results per flagged point
__global__ __launch_bounds__(256) void refine_merge_kernel(
    const PBest* __restrict__ pbest, const int* __restrict__ flagcnt,
    const int* __restrict__ flaglist, int* __restrict__ idx_cur,
    float* __restrict__ out_idx)
{
  int f = blockIdx.x * 256 + threadIdx.x;
  if (f >= *flagcnt) return;
  double best = 1e300; int bidx = 0x7fffffff;
  for (int ch = 0; ch < 4; ch++) {
    double d = pbest[f * 4 + ch].d; int j = pbest[f * 4 + ch].idx;
    if (d < best || (d == best && j < bidx)) { best = d; bidx = j; }
  }
  int n = flaglist[f];
  idx_cur[n] = bidx;
  out_idx[n] = (float)bidx;
}

// ------------------------------------------------------- trilinear upsample
__device__ inline void axis_map(int L, int outlen, int i, int* j0, int* j1, float* a0, float* a1) {
  if (L == 1) { *j0 = 0; *j1 = 0; *a0 = 1.f; *a1 = 0.f; return; }
  double scale = (double)L / (double)outlen;
  double src = (i + 0.5) * scale - 0.5;
  if (src < 0.0) src = 0.0;
  int i0 = (int)floor(src); if (i0 > L - 1) i0 = L - 1;
  int i1 = i0 + 1; if (i1 > L - 1) i1 = L - 1;
  double wv = src - (double)i0;
  if (i0 == i1) {
    float p = (float)(1.0 - wv), q = (float)wv;
    *a0 = p + q; *a1 = 0.f;
  } else { *a0 = (float)(1.0 - wv); *a1 = (float)wv; }
  *j0 = i0; *j1 = i1;
}

__global__ __launch_bounds__(256) void upsample_kernel(
    const float* __restrict__ emb, const int* __restrict__ idx_cur,
    double* __restrict__ hup, int tpn, int pn)
{
  int e = blockIdx.x * 256 + threadIdx.x;
  int c = e & 63, w = (e >> 6) & 15, h = (e >> 10) & 15, t = (e >> 14) & 3, b = e >> 16;
  int t0, t1, h0, h1, w0, w1; float ta0, ta1, ha0, ha1, wa0, wa1;
  axis_map(tpn, 4, t, &t0, &t1, &ta0, &ta1);
  axis_map(pn, 16, h, &h0, &h1, &ha0, &ha1);
  axis_map(pn, 16, w, &w0, &w1, &wa0, &wa1);
  int ti[2] = {t0, t1}; float ta[2] = {ta0, ta1};
  int hi[2] = {h0, h1}; float ha[2] = {ha0, ha1};
  int wi[2] = {w0, w1}; float wa[2] = {wa0, wa1};
  double val = 0.0;
  for (int a = 0; a < 2; a++)
    for (int bb = 0; bb < 2; bb++)
      for (int cc = 0; cc < 2; cc++) {
        double wgt = (double)ta[a] * (double)ha[bb] * (double)wa[cc];
        if (wgt != 0.0) {
          int code = idx_cur[((b * tpn + ti[a]) * pn + hi[bb]) * pn + wi[cc]];
          val += wgt * (double)emb[(size_t)code * 64 + c];
        }
      }
  hup[e] = val;
}

// ------------------------------------------- conv3d + accu update + commit
// grid 512 = b*64 + t*16 + h ; block 256 = 16w x 16co4 ; 1 h-row/thread.
__global__ __launch_bounds__(256) void conv_kernel(
    const double* __restrict__ hup, const float* __restrict__ twt, const float* __restrict__ bq,
    const float* __restrict__ zcl, double* __restrict__ accu, double* sse, int qi)
{
  __shared__ double hl[3][3][4][18];              // [tt][hh][cc][ww] halo, ci-chunk 4
  __shared__ __align__(16) float wl[27][4][64];   // [tap][cc][co] fp32 (exact)
  int bid = blockIdx.x;
  int b = bid >> 6, t = (bid >> 4) & 3, h = bid & 15;
  int tid = threadIdx.x;
  int co4 = tid >> 4;  // co = co4*4 .. +3
  int w = tid & 15;
  double acc[4] = {0.0, 0.0, 0.0, 0.0};
  for (int ci0 = 0; ci0 < 64; ci0 += 4) {
    __syncthreads();
    for (int i = tid; i < 648; i += 256) {
      int ww = i % 18; int r = i / 18; int cc = r & 3; r >>= 2; int hh = r % 3; int tt = r / 3;
      int gt = t - 1 + tt, gh = h - 1 + hh, gw = ww - 1;
      double v = 0.0;
      if (gt >= 0 && gt < 4 && gh >= 0 && gh < 16 && gw >= 0 && gw < 16)
        v = hup[(size_t)((((b * 4 + gt) * 16 + gh) * 16 + gw) * 64 + ci0 + cc)];
      hl[tt][hh][cc][ww] = v;
    }
    for (int i = tid; i < 6912; i += 256) {
      int co = i & 63; int r = i >> 6; int cc = r & 3; int tap = r >> 2;
      wl[tap][cc][co] = twt[(size_t)(((qi * 27 + tap) * 64 + ci0 + cc) * 64 + co)];
    }
    __syncthreads();
    for (int tap = 0; tap < 27; tap++) {
      int dt = tap / 9, dh = (tap / 3) % 3, dw = tap % 3;
#pragma unroll
      for (int cc = 0; cc < 4; cc++) {
        float4 wf = *(const float4*)&wl[tap][cc][co4 * 4];
        double hv = hl[dt][dh][cc][w + dw];
        acc[0] += hv * (double)wf.x; acc[1] += hv * (double)wf.y;
        acc[2] += hv * (double)wf.z; acc[3] += hv * (double)wf.w;
      }
    }
  }
  double lsse = 0.0;
#pragma unroll
  for (int q = 0; q < 4; q++) {
    int co = co4 * 4 + q;
    size_t off = (size_t)((((b * 4 + t) * 16 + h) * 16 + w) * 64 + co);
    double conv = acc[q] + (double)bq[qi * 64 + co];
    double hu = hup[off];
    double na = accu[off] + 0.5 * hu + 0.5 * conv;  // h*(1-q) + conv*q, q=0.5
    accu[off] = na;
    double df = na - (double)zcl[off];
    lsse += df * df;
  }
#pragma unroll
  for (int o = 32; o > 0; o >>= 1) lsse += __shfl_down(lsse, o);
  if ((tid & 63) == 0) atomicAdd(sse, lsse);
}

// ---------------------------------------------------------------- stats
__global__ __launch_bounds__(256) void bincount_kernel(const int* __restrict__ idx_cur, int* counts) {
  int i = blockIdx.x * 256 + threadIdx.x;
  if (i < NSP) atomicAdd(&counts[idx_cur[i]], 1);
}

__global__ __launch_bounds__(256) void stats_kernel(
    const int* __restrict__ counts, float* __restrict__ usage_out, double* ent, int* usedcnt)
{
  __shared__ double re[256];
  __shared__ int ru[256];
  int j = blockIdx.x * 256 + threadIdx.x;
  int cnt = counts[j];
  double p = (double)cnt / 8192.0;
  usage_out[j] = (float)p;
  re[threadIdx.x] = p * log(p + 1e-10);
  ru[threadIdx.x] = cnt > 0 ? 1 : 0;
  __syncthreads();
  for (int s = 128; s > 0; s >>= 1) {
    if (threadIdx.x < s) { re[threadIdx.x] += re[threadIdx.x + s]; ru[threadIdx.x] += ru[threadIdx.x + s]; }
    __syncthreads();
  }
  if (threadIdx.x == 0) { atomicAdd(ent, re[0]); atomicAdd(usedcnt, ru[0]); }
}

__global__ void final_kernel(const double* sse, const double* ent, const int* usedcnt, float* out) {
  if (threadIdx.x == 0) {
    out[NELEM]     = (float)(*sse * 0.25 / 524288.0 / 10.0);
    out[NELEM + 1] = (float)exp(-*ent);
    out[NELEM + 2] = (float)((double)*usedcnt / 16384.0);
  }
}

__global__ __launch_bounds__(256) void embst_kernel(const double* __restrict__ accu, float* __restrict__ out) {
  int e = blockIdx.x * 256 + threadIdx.x;
  int w = e & 15, h = (e >> 4) & 15, t = (e >> 8) & 3, c = (e >> 10) & 63, b = e >> 16;
  out[e] = (float)accu[(size_t)(((((b * 4 + t) * 16 + h) * 16 + w) * 64) + c)];
}

// ---------------------------------------------------------------- launch
extern "C" void kernel_launch(void* const* d_in, const int* in_sizes, int n_in,
                              void* d_out, int out_size, void* d_ws, size_t ws_size,
                              hipStream_t stream) {
  static const int T_PN_h[10] = {1, 1, 2, 2, 2, 4, 4, 4, 4, 4};
  static const int V_PN_h[10] = {1, 2, 3, 4, 5, 6, 8, 10, 13, 16};
  // qi from bit-exact fp64 emulation of np.linspace+argmin (ties: si=2->1, si=7->3)
  static const int QI_h[10]   = {0, 0, 1, 1, 1, 2, 2, 3, 3, 3};
  static const int NS_h[10]   = {8, 32, 144, 256, 400, 1152, 2048, 3200, 5408, 8192};
  static const int OB_h[10]   = {540675, 540683, 540715, 540859, 541115,
                                 541515, 542667, 544715, 547915, 553323};

  const float* z   = (const float*)d_in[0];
  const float* emb = (const float*)d_in[1];
  const float* Wq  = (const float*)d_in[2];
  const float* bq  = (const float*)d_in[3];
  float* out = (float*)d_out;
  char* ws = (char*)d_ws;

  double* accu    = (double*)(ws + WS_ACCU);
  double* hup     = (double*)(ws + WS_HUP);
  double* rest64  = (double*)(ws + WS_REST64);
  float4* part    = (float4*)(ws + WS_PART);
  PBest*  pbest   = (PBest*)(ws + WS_PART);
  float*  zcl     = (float*)(ws + WS_ZCL);
  short*  ehf     = (short*)(ws + WS_EHF);
  short*  elf     = (short*)(ws + WS_ELF);
  float*  esq     = (float*)(ws + WS_ESQ);
  float*  twt     = (float*)(ws + WS_TWT);
  int*    idx_cur = (int*)(ws + WS_IDX);
  int*    counts  = (int*)(ws + WS_CNT);
  int*    flaglist= (int*)(ws + WS_FLAGL);
  int*    flagcnt = (int*)(ws + WS_FLAGC);
  double* sse     = (double*)(ws + WS_SSE);
  double* ent     = (double*)(ws + WS_ENT);
  int*    usedcnt = (int*)(ws + WS_USED);
  short*  rhf     = (short*)(ws + WS_RHF);
  short*  rlf     = (short*)(ws + WS_RLF);

  prep_kernel<<<10049, 256, 0, stream>>>(z, emb, Wq, accu, zcl, ehf, elf, esq, twt,
                                         counts, flagcnt, sse, ent, usedcnt);

  for (int si = 0; si < 10; si++) {
    int tpn = T_PN_h[si], pn = V_PN_h[si], N = NS_h[si];
    int NSpad = (N + 63) & ~63;
    pool_kernel<<<NSpad, 256, 0, stream>>>(zcl, accu, rest64, rhf, rlf, N, tpn, pn);
    dim3 ag(NSpad / 64, 16);
    argmin_kernel<<<ag, 256, 0, stream>>>(rhf, rlf, ehf, elf, esq, part);
    reduce_kernel<<<(N + 255) / 256, 256, 0, stream>>>(part, idx_cur, out + OB_h[si],
                                                       flagcnt + si, flaglist, N);
    dim3 rg(N, 4);   // flags <= N; null blocks exit on flagcnt read
    refine_kernel<<<rg, 256, 0, stream>>>(rest64, emb, flagcnt + si, flaglist, pbest);
    refine_merge_kernel<<<(N + 255) / 256, 256, 0, stream>>>(pbest, flagcnt + si, flaglist,
                                                             idx_cur, out + OB_h[si]);
    upsample_kernel<<<NELEM / 256, 256, 0, stream>>>(emb, idx_cur, hup, tpn, pn);
    conv_kernel<<<512, 256, 0, stream>>>(hup, twt, bq, zcl, accu, sse, QI_h[si]);
  }

  bincount_kernel<<<32, 256, 0, stream>>>(idx_cur, counts);
  stats_kernel<<<64, 256, 0, stream>>>(counts, out + 524291, ent, usedcnt);
  final_kernel<<<1, 64, 0, stream>>>(sse, ent, usedcnt, out);
  embst_kernel<<<NELEM / 256, 256, 0, stream>>>(accu, out);
}

// Round 10
// 2432.607 us; speedup vs baseline: 1.8443x; 1.0368x over previous
//
#include <hip/hip_runtime.h>
#include <math.h>

// MultiScaleCodebook on MI355X — round 10: conv LDS-byte diet.
// r9 post-mortem: conv LDS-BW-bound (6 B/FMA -> 5.4 GB/scale -> ~103us floor,
// 133 observed). Fix: thread = 2w x 4co (wgt amortized over w-pair, hv over
// co) -> 4 B/FMA; ci-range split in 2 across blocks (grid 512 = b,t,h-pair,
// ci-half) for 8 waves/CU; partials to pacc (aliases dead rest64+part, 8MB),
// combine kernel does (p0+p1)+bias, 0.5/0.5 mix, accu, sse. fp64 reorder
// across split ~1e-16 (same class as r4 pool reorder — passing since r4).

#define NCODES 16384
#define NELEM  524288   // 8*64*4*16*16
#define NSP    8192     // 8*4*16*16

#define WS_ACCU   0ul
#define WS_HUP    4194304ul
#define WS_REST64 8388608ul
#define WS_PACC   8388608ul    // conv partials [2][NELEM] f64 = 8MB; aliases
                               // rest64(dead after refine)+part(dead after merge)
#define WS_PART   12582912ul   // 2MB used of 4MB slot; refine pbest aliases this
#define WS_ZCL    16777216ul
#define WS_EHF    18874368ul   // emb bf16-hi frags, 2MB
#define WS_ELF    20971520ul   // emb bf16-lo frags, 2MB
#define WS_ESQ    23068672ul
#define WS_TWT    23134208ul
#define WS_IDX    24903680ul
#define WS_CNT    24936448ul
#define WS_FLAGL  25001984ul
#define WS_FLAGC  25034752ul
#define WS_SSE    25034816ul
#define WS_ENT    25034824ul
#define WS_USED   25034832ul
#define WS_RHF    25034848ul   // rest bf16-hi frags, 1MB
#define WS_RLF    26083424ul   // rest bf16-lo frags, 1MB

typedef __attribute__((ext_vector_type(8))) short short8;
typedef __attribute__((ext_vector_type(4))) float floatx4;

struct PBest { double d; int idx; int pad; };

// round-to-nearest-even float -> bf16; also returns hi as float
__device__ inline short bf16rne(float f, float* hi) {
  unsigned u = __float_as_uint(f);
  unsigned r = (u + 0x7FFFu + ((u >> 16) & 1u)) >> 16;
  *hi = __uint_as_float(r << 16);
  return (short)r;
}

// ---------------------------------------------------------------- prep
__global__ __launch_bounds__(256) void prep_kernel(
    const float* __restrict__ z, const float* __restrict__ emb, const float* __restrict__ Wq,
    double* __restrict__ accu, float* __restrict__ zcl,
    short* __restrict__ ehf, short* __restrict__ elf,
    float* __restrict__ esq, float* __restrict__ twt,
    int* __restrict__ counts, int* __restrict__ flagcnt,
    double* sse, double* ent, int* usedcnt)
{
  int i = blockIdx.x * 256 + threadIdx.x;
  if (i < NELEM) { accu[i] = 0.0; return; }
  i -= NELEM;
  if (i < NELEM) {  // z [B,C,T,H,W] -> zcl [B,T,H,W,C]
    int c = i & 63, w = (i >> 6) & 15, h = (i >> 10) & 15, t = (i >> 14) & 3, b = i >> 16;
    zcl[i] = z[(((b * 64 + c) * 4 + t) * 16 + h) * 16 + w];
    return;
  }
  i -= NELEM;
  if (i < NCODES * 64) {  // emb -> bf16 split, MFMA B-frag order
    int j = i >> 6, c = i & 63;
    float v = emb[i];
    float hi; short h = bf16rne(v, &hi);
    float hi2; short l = bf16rne(v - hi, &hi2);
    int jt = j >> 4, nn = j & 15, hf = c >> 5, q = (c >> 3) & 3, ii = c & 7;
    size_t slot = ((size_t)(((jt * 2 + hf) * 64) + q * 16 + nn)) * 8 + ii;
    ehf[slot] = h; elf[slot] = l;
    return;
  }
  i -= NCODES * 64;
  if (i < NCODES) {  // e_sq fp32 (ranking only; refine is fp64)
    float s = 0.f;
    for (int c = 0; c < 64; c++) { float v = emb[i * 64 + c]; s += v * v; }
    esq[i] = s; return;
  }
  i -= NCODES;
  if (i < 442368) {  // twt[qi][tap][ci][co] = Wq[qi][co][ci][tap]
    int qi = i / 110592; int r = i % 110592;
    int tap = r >> 12; int ci = (r >> 6) & 63; int co = r & 63;
    twt[i] = Wq[((qi * 64 + co) * 64 + ci) * 27 + tap];
    return;
  }
  i -= 442368;
  if (i < NCODES) { counts[i] = 0; return; }
  i -= NCODES;
  if (i < 16) {
    if (i < 10) flagcnt[i] = 0;
    else if (i == 10) *sse = 0.0;
    else if (i == 11) *ent = 0.0;
    else if (i == 12) *usedcnt = 0;
  }
}

// ------------------------------------------- pool (area) + frag emit
__global__ __launch_bounds__(256) void pool_kernel(
    const float* __restrict__ zcl, const double* __restrict__ accu,
    double* __restrict__ rest64, short* __restrict__ rhf, short* __restrict__ rlf,
    int N, int tpn, int pn)
{
  __shared__ double psum[4][64];
  int n = blockIdx.x;
  int tid = threadIdx.x;
  int c = tid & 63, ck = tid >> 6;
  if (n >= N) {  // zero pad rows so argmin frags are defined
    if (tid < 64) {
      int pt = n >> 4, m = n & 15, hf = tid >> 5, q = (tid >> 3) & 3, ii = tid & 7;
      size_t slot = ((size_t)(((pt * 2 + hf) * 64) + q * 16 + m)) * 8 + ii;
      rhf[slot] = 0; rlf[slot] = 0;
    }
    return;
  }
  int ppn = pn * pn;
  int b = n / (tpn * ppn); int r = n % (tpn * ppn);
  int u = r / ppn; r %= ppn; int v = r / pn; int x = r % pn;
  int t0 = (u * 4) / tpn, t1 = ((u + 1) * 4 + tpn - 1) / tpn;
  int h0 = (v * 16) / pn, h1 = ((v + 1) * 16 + pn - 1) / pn;
  int w0 = (x * 16) / pn, w1 = ((x + 1) * 16 + pn - 1) / pn;
  int nt = t1 - t0, nh = h1 - h0, nw = w1 - w0;
  int M = nt * nh * nw;
  int chunk = (M + 3) >> 2;
  int m0 = ck * chunk; int m1 = m0 + chunk; if (m1 > M) m1 = M;
  double s = 0.0;
  if (m0 < m1) {
    int tmp = m0 / nw; int wi = m0 - tmp * nw;
    int ti = tmp / nh; int hi = tmp - ti * nh;
    for (int m = m0; m < m1; m++) {
      size_t off = (size_t)((((b * 4 + t0 + ti) * 16 + h0 + hi) * 16 + w0 + wi) * 64 + c);
      s += (double)zcl[off] - accu[off];
      if (++wi == nw) { wi = 0; if (++hi == nh) { hi = 0; ++ti; } }
    }
  }
  psum[ck][c] = s;
  __syncthreads();
  if (tid < 64) {
    double t = ((psum[0][c] + psum[1][c]) + psum[2][c]) + psum[3][c];
    float wt = 1.f / (float)nt, wh = 1.f / (float)nh, ww = 1.f / (float)nw;
    double rv = t * (double)wt * (double)wh * (double)ww;
    rest64[(size_t)n * 64 + c] = rv;
    float rv32 = (float)rv;
    float hi; short h = bf16rne(rv32, &hi);
    float hi2; short l = bf16rne(rv32 - hi, &hi2);
    int pt = n >> 4, m = n & 15, hf = c >> 5, q = (c >> 3) & 3, ii = c & 7;
    size_t slot = ((size_t)(((pt * 2 + hf) * 64) + q * 16 + m)) * 8 + ii;
    rhf[slot] = h; rlf[slot] = l;
  }
}

// ------------------------------------------- argmin pass 1 (bf16 MFMA GEMM)
__global__ __launch_bounds__(256) void argmin_kernel(
    const short* __restrict__ rhf, const short* __restrict__ rlf,
    const short* __restrict__ ehf, const short* __restrict__ elf,
    const float* __restrict__ esq, float4* __restrict__ part)
{
  __shared__ short8 Ah[4][2][64];
  __shared__ short8 Al[4][2][64];
  __shared__ short8 Bh[8][2][64];
  __shared__ short8 Bl[8][2][64];
  __shared__ float esql[128];
  int tid = threadIdx.x;
  int pbase = blockIdx.x * 64;
  int ch = blockIdx.y;
  {
    const short8* sH = (const short8*)(rhf + (size_t)pbase * 64);
    const short8* sL = (const short8*)(rlf + (size_t)pbase * 64);
    short8* dH = (short8*)Ah; short8* dL = (short8*)Al;
    dH[tid] = sH[tid]; dH[tid + 256] = sH[tid + 256];
    dL[tid] = sL[tid]; dL[tid + 256] = sL[tid + 256];
  }
  __syncthreads();
  int w = tid >> 6, lane = tid & 63, col = lane & 15;
  short8 ah0 = Ah[w][0][lane], ah1 = Ah[w][1][lane];
  short8 al0 = Al[w][0][lane], al1 = Al[w][1][lane];
  float m1[4], m2[4]; int i1[4];
#pragma unroll
  for (int r = 0; r < 4; r++) { m1[r] = 3.4e38f; m2[r] = 3.4e38f; i1[r] = 0x7fffffff; }
  for (int s = 0; s < 8; s++) {
    int j0 = ch * 1024 + s * 128;
    __syncthreads();
    {
      const short8* sH = (const short8*)(ehf + (size_t)j0 * 64);
      const short8* sL = (const short8*)(elf + (size_t)j0 * 64);
      short8* dH = (short8*)Bh; short8* dL = (short8*)Bl;
#pragma unroll
      for (int it = 0; it < 4; it++) { dH[tid + it * 256] = sH[tid + it * 256]; dL[tid + it * 256] = sL[tid + it * 256]; }
      if (tid < 128) esql[tid] = esq[j0 + tid];
    }
    __syncthreads();
    floatx4 acc[8];
#pragma unroll
    for (int jt = 0; jt < 8; jt++) acc[jt] = (floatx4){0.f, 0.f, 0.f, 0.f};
#pragma unroll
    for (int jt = 0; jt < 8; jt++) {
      short8 bh0 = Bh[jt][0][lane], bl0 = Bl[jt][0][lane];
      short8 bh1 = Bh[jt][1][lane], bl1 = Bl[jt][1][lane];
      acc[jt] = __builtin_amdgcn_mfma_f32_16x16x32_bf16(al0, bh0, acc[jt], 0, 0, 0);
      acc[jt] = __builtin_amdgcn_mfma_f32_16x16x32_bf16(ah0, bl0, acc[jt], 0, 0, 0);
      acc[jt] = __builtin_amdgcn_mfma_f32_16x16x32_bf16(ah0, bh0, acc[jt], 0, 0, 0);
      acc[jt] = __builtin_amdgcn_mfma_f32_16x16x32_bf16(al1, bh1, acc[jt], 0, 0, 0);
      acc[jt] = __builtin_amdgcn_mfma_f32_16x16x32_bf16(ah1, bl1, acc[jt], 0, 0, 0);
      acc[jt] = __builtin_amdgcn_mfma_f32_16x16x32_bf16(ah1, bh1, acc[jt], 0, 0, 0);
    }
#pragma unroll
    for (int jt = 0; jt < 8; jt++) {
      float es = esql[jt * 16 + col];
      int j = j0 + jt * 16 + col;
#pragma unroll
      for (int r = 0; r < 4; r++) {
        float d = fmaf(-2.f, acc[jt][r], es);
        if (d < m1[r]) { m2[r] = m1[r]; m1[r] = d; i1[r] = j; }
        else if (d < m2[r]) { m2[r] = d; }
      }
    }
  }
#pragma unroll
  for (int off = 1; off < 16; off <<= 1) {
#pragma unroll
    for (int r = 0; r < 4; r++) {
      float o1 = __shfl_xor(m1[r], off);
      int   oi = __shfl_xor(i1[r], off);
      float o2 = __shfl_xor(m2[r], off);
      bool bwin = (o1 < m1[r]) || (o1 == m1[r] && oi < i1[r]);
      float nm2 = bwin ? fminf(m1[r], o2) : fminf(m2[r], o1);
      if (bwin) { m1[r] = o1; i1[r] = oi; }
      m2[r] = nm2;
    }
  }
  if (col == 0) {
    int quad = lane >> 4;
#pragma unroll
    for (int r = 0; r < 4; r++) {
      int p = pbase + w * 16 + quad * 4 + r;
      part[(size_t)ch * NSP + p] = make_float4(m1[r], m2[r], __int_as_float(i1[r]), 0.f);
    }
  }
}

// ---------------------------- merge chunks, flag near-ties to global list
__global__ __launch_bounds__(256) void reduce_kernel(
    const float4* __restrict__ part, int* __restrict__ idx_cur,
    float* __restrict__ out_idx, int* flagcnt, int* flaglist, int N)
{
  int n = blockIdx.x * 256 + threadIdx.x;
  if (n >= N) return;
  float m1 = 3.4e38f, m2 = 3.4e38f; int i1 = 0x7fffffff;
  for (int ch = 0; ch < 16; ch++) {
    float4 q = part[(size_t)ch * NSP + n];
    float o1 = q.x, o2 = q.y; int oi = __float_as_int(q.z);
    bool bwin = (o1 < m1) || (o1 == m1 && oi < i1);
    float nm2 = bwin ? fminf(m1, o2) : fminf(m2, o1);
    if (bwin) { m1 = o1; i1 = oi; }
    m2 = nm2;
  }
  idx_cur[n] = i1;
  out_idx[n] = (float)i1;
  if (m2 - m1 < 0.01f) {
    int pos = atomicAdd(flagcnt, 1);
    flaglist[pos] = n;
  }
}

// -------------------- parallel fp64 rescan: block = (flag, 4096-code chunk)
__global__ __launch_bounds__(256) void refine_kernel(
    const double* __restrict__ rest64, const float* __restrict__ emb,
    const int* __restrict__ flagcnt, const int* __restrict__ flaglist,
    PBest* __restrict__ pbest)
{
  __shared__ double rl[64];
  __shared__ double bm[256];
  __shared__ int    bi[256];
  int f = blockIdx.x;
  if (f >= *flagcnt) return;
  int ch = blockIdx.y;
  int tid = threadIdx.x;
  int n = flaglist[f];
  if (tid < 64) rl[tid] = rest64[(size_t)n * 64 + tid];
  __syncthreads();
  double best = 1e300; int bidx = 0x7fffffff;
#pragma unroll 1
  for (int k = 0; k < 16; k++) {
    int j = ch * 4096 + k * 256 + tid;
    double d = 0.0;
    const float4* ej = (const float4*)&emb[(size_t)j * 64];
#pragma unroll
    for (int c4 = 0; c4 < 16; c4++) {
      float4 ev = ej[c4];
      double d0 = rl[c4 * 4 + 0] - (double)ev.x;
      double d1 = rl[c4 * 4 + 1] - (double)ev.y;
      double d2 = rl[c4 * 4 + 2] - (double)ev.z;
      double d3 = rl[c4 * 4 + 3] - (double)ev.w;
      d += d0 * d0; d += d1 * d1; d += d2 * d2; d += d3 * d3;
    }
    if (d < best) { best = d; bidx = j; }  // ascending j keeps first min
  }
  bm[tid] = best; bi[tid] = bidx;
  __syncthreads();
  for (int s = 128; s > 0; s >>= 1) {
    if (tid < s) {
      double ob = bm[tid + s]; int oi = bi[tid + s];
      if (ob < bm[tid] || (ob == bm[tid] && oi < bi[tid])) { bm[tid] = ob; bi[tid] = oi; }
    }
    __syncthreads();
  }
  if (tid == 0) { pbest[f * 4 + ch].d = bm[0]; pbest[f * 4 + ch].idx = bi[0]; }
}

// -------------------------------- fold 4 chunk results per flagged point
__global__ __launch_bounds__(256) void refine_merge_kernel(
    const PBest* __restrict__ pbest, const int* __restrict__ flagcnt,
    const int* __restrict__ flaglist, int* __restrict__ idx_cur,
    float* __restrict__ out_idx)
{
  int f = blockIdx.x * 256 + threadIdx.x;
  if (f >= *flagcnt) return;
  double best = 1e300; int bidx = 0x7fffffff;
  for (int ch = 0; ch < 4; ch++) {
    double d = pbest[f * 4 + ch].d; int j = pbest[f * 4 + ch].idx;
    if (d < best || (d == best && j < bidx)) { best = d; bidx = j; }
  }
  int n = flaglist[f];
  idx_cur[n] = bidx;
  out_idx[n] = (float)bidx;
}

// ------------------------------------------------------- trilinear upsample
__device__ inline void axis_map(int L, int outlen, int i, int* j0, int* j1, float* a0, float* a1) {
  if (L == 1) { *j0 = 0; *j1 = 0; *a0 = 1.f; *a1 = 0.f; return; }
  double scale = (double)L / (double)outlen;
  double src = (i + 0.5) * scale - 0.5;
  if (src < 0.0) src = 0.0;
  int i0 = (int)floor(src); if (i0 > L - 1) i0 = L - 1;
  int i1 = i0 + 1; if (i1 > L - 1) i1 = L - 1;
  double wv = src - (double)i0;
  if (i0 == i1) {
    float p = (float)(1.0 - wv), q = (float)wv;
    *a0 = p + q; *a1 = 0.f;
  } else { *a0 = (float)(1.0 - wv); *a1 = (float)wv; }
  *j0 = i0; *j1 = i1;
}

__global__ __launch_bounds__(256) void upsample_kernel(
    const float* __restrict__ emb, const int* __restrict__ idx_cur,
    double* __restrict__ hup, int tpn, int pn)
{
  int e = blockIdx.x * 256 + threadIdx.x;
  int c = e & 63, w = (e >> 6) & 15, h = (e >> 10) & 15, t = (e >> 14) & 3, b = e >> 16;
  int t0, t1, h0, h1, w0, w1; float ta0, ta1, ha0, ha1, wa0, wa1;
  axis_map(tpn, 4, t, &t0, &t1, &ta0, &ta1);
  axis_map(pn, 16, h, &h0, &h1, &ha0, &ha1);
  axis_map(pn, 16, w, &w0, &w1, &wa0, &wa1);
  int ti[2] = {t0, t1}; float ta[2] = {ta0, ta1};
  int hi[2] = {h0, h1}; float ha[2] = {ha0, ha1};
  int wi[2] = {w0, w1}; float wa[2] = {wa0, wa1};
  double val = 0.0;
  for (int a = 0; a < 2; a++)
    for (int bb = 0; bb < 2; bb++)
      for (int cc = 0; cc < 2; cc++) {
        double wgt = (double)ta[a] * (double)ha[bb] * (double)wa[cc];
        if (wgt != 0.0) {
          int code = idx_cur[((b * tpn + ti[a]) * pn + hi[bb]) * pn + wi[cc]];
          val += wgt * (double)emb[(size_t)code * 64 + c];
        }
      }
  hup[e] = val;
}

// --------------------- conv3d partial (ci-half) — 2w x 4co per thread
// grid 512: bid = [b:3][t:2][hp:3][s:1]; block 256 = th2 x wp8 x co4(16).
// Per (tap,cc): 1 b128 wgt (shared over w-pair) + 2 f64 hv (shared over co)
// -> 4 B/FMA LDS. Partials pacc[s][elem]; combine adds s0+s1 + bias.
__global__ __launch_bounds__(256) void conv_part_kernel(
    const double* __restrict__ hup, const float* __restrict__ twt,
    double* __restrict__ pacc, int qi)
{
  __shared__ double hl[4][3][4][18];              // [cc][tt][hh][ww] 10368 B
  __shared__ __align__(16) float wl[27][4][64];   // [tap][cc][co] 27648 B
  int bid = blockIdx.x;
  int s = bid & 1, hp = (bid >> 1) & 7, t = (bid >> 4) & 3, b = bid >> 6;
  int tid = threadIdx.x;
  int co4 = tid & 15;        // co = co4*4
  int wp  = (tid >> 4) & 7;  // w0 = wp*2
  int th  = tid >> 7;        // h = hp*2 + th
  int h = hp * 2 + th, w0 = wp * 2;
  double acc0[4] = {0.0, 0.0, 0.0, 0.0};
  double acc1[4] = {0.0, 0.0, 0.0, 0.0};
  for (int ci0 = s * 32; ci0 < s * 32 + 32; ci0 += 4) {
    __syncthreads();
    // halo: 4cc x 3tt x 4hh x 18ww = 864 (hh covers hp*2-1 .. hp*2+2)
    for (int i = tid; i < 864; i += 256) {
      int ww = i % 18; int r = i / 18;
      int hh = r & 3; r >>= 2; int tt = r % 3; int cc = r / 3;
      int gt = t - 1 + tt, gh = hp * 2 - 1 + hh, gw = ww - 1;
      double v = 0.0;
      if (gt >= 0 && gt < 4 && gh >= 0 && gh < 16 && gw >= 0 && gw < 16)
        v = hup[(size_t)((((b * 4 + gt) * 16 + gh) * 16 + gw) * 64 + ci0 + cc)];
      hl[cc][tt][hh][ww] = v;
    }
    for (int i = tid; i < 6912; i += 256) {
      int co = i & 63; int r = i >> 6; int cc = r & 3; int tap = r >> 2;
      wl[tap][cc][co] = twt[(size_t)(((qi * 27 + tap) * 64 + ci0 + cc) * 64 + co)];
    }
    __syncthreads();
    for (int tap = 0; tap < 27; tap++) {
      int dt = tap / 9, dh = (tap / 3) % 3, dw = tap % 3;
#pragma unroll
      for (int cc = 0; cc < 4; cc++) {
        float4 wf = *(const float4*)&wl[tap][cc][co4 * 4];
        double hva = hl[cc][dt][th + dh][w0 + dw];
        double hvb = hl[cc][dt][th + dh][w0 + 1 + dw];
        double w0d = (double)wf.x, w1d = (double)wf.y, w2d = (double)wf.z, w3d = (double)wf.w;
        acc0[0] += hva * w0d; acc0[1] += hva * w1d; acc0[2] += hva * w2d; acc0[3] += hva * w3d;
        acc1[0] += hvb * w0d; acc1[1] += hvb * w1d; acc1[2] += hvb * w2d; acc1[3] += hvb * w3d;
      }
    }
  }
  size_t e0 = (size_t)((((b * 4 + t) * 16 + h) * 16 + w0) * 64 + co4 * 4);
  double* d0 = &pacc[(size_t)s * NELEM + e0];
#pragma unroll
  for (int q = 0; q < 4; q++) d0[q] = acc0[q];
#pragma unroll
  for (int q = 0; q < 4; q++) d0[64 + q] = acc1[q];
}

// ------------------- combine partials + bias + 0.5/0.5 mix + accu + sse
__global__ __launch_bounds__(256) void conv_combine_kernel(
    const double* __restrict__ pacc, const double* __restrict__ hup,
    const float* __restrict__ bq, const float* __restrict__ zcl,
    double* __restrict__ accu, double* sse, int qi)
{
  __shared__ double red[256];
  int tid = threadIdx.x;
  int e = blockIdx.x * 256 + tid;
  int co = e & 63;
  double cv = (pacc[e] + pacc[(size_t)NELEM + e]) + (double)bq[qi * 64 + co];
  double hu = hup[e];
  double na = accu[e] + 0.5 * hu + 0.5 * cv;  // h*(1-q) + conv*q, q=0.5
  accu[e] = na;
  double df = na - (double)zcl[e];
  red[tid] = df * df;
  __syncthreads();
  for (int s = 128; s > 0; s >>= 1) { if (tid < s) red[tid] += red[tid + s]; __syncthreads(); }
  if (tid == 0) atomicAdd(sse, red[0]);
}

// ---------------------------------------------------------------- stats
__global__ __launch_bounds__(256) void bincount_kernel(const int* __restrict__ idx_cur, int* counts) {
  int i = blockIdx.x * 256 + threadIdx.x;
  if (i < NSP) atomicAdd(&counts[idx_cur[i]], 1);
}

__global__ __launch_bounds__(256) void stats_kernel(
    const int* __restrict__ counts, float* __restrict__ usage_out, double* ent, int* usedcnt)
{
  __shared__ double re[256];
  __shared__ int ru[256];
  int j = blockIdx.x * 256 + threadIdx.x;
  int cnt = counts[j];
  double p = (double)cnt / 8192.0;
  usage_out[j] = (float)p;
  re[threadIdx.x] = p * log(p + 1e-10);
  ru[threadIdx.x] = cnt > 0 ? 1 : 0;
  __syncthreads();
  for (int s = 128; s > 0; s >>= 1) {
    if (threadIdx.x < s) { re[threadIdx.x] += re[threadIdx.x + s]; ru[threadIdx.x] += ru[threadIdx.x + s]; }
    __syncthreads();
  }
  if (threadIdx.x == 0) { atomicAdd(ent, re[0]); atomicAdd(usedcnt, ru[0]); }
}

__global__ void final_kernel(const double* sse, const double* ent, const int* usedcnt, float* out) {
  if (threadIdx.x == 0) {
    out[NELEM]     = (float)(*sse * 0.25 / 524288.0 / 10.0);
    out[NELEM + 1] = (float)exp(-*ent);
    out[NELEM + 2] = (float)((double)*usedcnt / 16384.0);
  }
}

__global__ __launch_bounds__(256) void embst_kernel(const double* __restrict__ accu, float* __restrict__ out) {
  int e = blockIdx.x * 256 + threadIdx.x;
  int w = e & 15, h = (e >> 4) & 15, t = (e >> 8) & 3, c = (e >> 10) & 63, b = e >> 16;
  out[e] = (float)accu[(size_t)(((((b * 4 + t) * 16 + h) * 16 + w) * 64) + c)];
}

// ---------------------------------------------------------------- launch
extern "C" void kernel_launch(void* const* d_in, const int* in_sizes, int n_in,
                              void* d_out, int out_size, void* d_ws, size_t ws_size,
                              hipStream_t stream) {
  static const int T_PN_h[10] = {1, 1, 2, 2, 2, 4, 4, 4, 4, 4};
  static const int V_PN_h[10] = {1, 2, 3, 4, 5, 6, 8, 10, 13, 16};
  // qi from bit-exact fp64 emulation of np.linspace+argmin (ties: si=2->1, si=7->3)
  static const int QI_h[10]   = {0, 0, 1, 1, 1, 2, 2, 3, 3, 3};
  static const int NS_h[10]   = {8, 32, 144, 256, 400, 1152, 2048, 3200, 5408, 8192};
  static const int OB_h[10]   = {540675, 540683, 540715, 540859, 541115,
                                 541515, 542667, 544715, 547915, 553323};

  const float* z   = (const float*)d_in[0];
  const float* emb = (const float*)d_in[1];
  const float* Wq  = (const float*)d_in[2];
  const float* bq  = (const float*)d_in[3];
  float* out = (float*)d_out;
  char* ws = (char*)d_ws;

  double* accu    = (double*)(ws + WS_ACCU);
  double* hup     = (double*)(ws + WS_HUP);
  double* rest64  = (double*)(ws + WS_REST64);
  double* pacc    = (double*)(ws + WS_PACC);   // aliases rest64+part (dead in conv)
  float4* part    = (float4*)(ws + WS_PART);
  PBest*  pbest   = (PBest*)(ws + WS_PART);
  float*  zcl     = (float*)(ws + WS_ZCL);
  short*  ehf     = (short*)(ws + WS_EHF);
  short*  elf     = (short*)(ws + WS_ELF);
  float*  esq     = (float*)(ws + WS_ESQ);
  float*  twt     = (float*)(ws + WS_TWT);
  int*    idx_cur = (int*)(ws + WS_IDX);
  int*    counts  = (int*)(ws + WS_CNT);
  int*    flaglist= (int*)(ws + WS_FLAGL);
  int*    flagcnt = (int*)(ws + WS_FLAGC);
  double* sse     = (double*)(ws + WS_SSE);
  double* ent     = (double*)(ws + WS_ENT);
  int*    usedcnt = (int*)(ws + WS_USED);
  short*  rhf     = (short*)(ws + WS_RHF);
  short*  rlf     = (short*)(ws + WS_RLF);

  prep_kernel<<<10049, 256, 0, stream>>>(z, emb, Wq, accu, zcl, ehf, elf, esq, twt,
                                         counts, flagcnt, sse, ent, usedcnt);

  for (int si = 0; si < 10; si++) {
    int tpn = T_PN_h[si], pn = V_PN_h[si], N = NS_h[si];
    int NSpad = (N + 63) & ~63;
    pool_kernel<<<NSpad, 256, 0, stream>>>(zcl, accu, rest64, rhf, rlf, N, tpn, pn);
    dim3 ag(NSpad / 64, 16);
    argmin_kernel<<<ag, 256, 0, stream>>>(rhf, rlf, ehf, elf, esq, part);
    reduce_kernel<<<(N + 255) / 256, 256, 0, stream>>>(part, idx_cur, out + OB_h[si],
                                                       flagcnt + si, flaglist, N);
    dim3 rg(N, 4);   // flags <= N; null blocks exit on flagcnt read
    refine_kernel<<<rg, 256, 0, stream>>>(rest64, emb, flagcnt + si, flaglist, pbest);
    refine_merge_kernel<<<(N + 255) / 256, 256, 0, stream>>>(pbest, flagcnt + si, flaglist,
                                                             idx_cur, out + OB_h[si]);
    upsample_kernel<<<NELEM / 256, 256, 0, stream>>>(emb, idx_cur, hup, tpn, pn);
    conv_part_kernel<<<512, 256, 0, stream>>>(hup, twt, pacc, QI_h[si]);
    conv_combine_kernel<<<NELEM / 256, 256, 0, stream>>>(pacc, hup, bq, zcl, accu, sse, QI_h[si]);
  }

  bincount_kernel<<<32, 256, 0, stream>>>(idx_cur, counts);
  stats_kernel<<<64, 256, 0, stream>>>(counts, out + 524291, ent, usedcnt);
  final_kernel<<<1, 64, 0, stream>>>(sse, ent, usedcnt, out);
  embst_kernel<<<NELEM / 256, 256, 0, stream>>>(accu, out);
}

// Round 11
// 2397.332 us; speedup vs baseline: 1.8715x; 1.0147x over previous
//
#include <hip/hip_runtime.h>
#include <math.h>

// MultiScaleCodebook on MI355X — round 11: argmin adaptive chunks + max-scan.
// r10 post-mortem: argmin top (118us @N=8192, VALUBusy 72%/Mfma 18%); small
// scales run 16 blocks -> latency-bound ~35us each. Fix 1: runtime chunk
// count nch (64/32/16 chunks of 256/512/1024 codes) -> small scales 4x more
// parallel, mid scales better CU balance. Fix 2: esq folded into MFMA C-init
// (acc starts at -es/2) -> scan is a pure max-scan, d=-2a written to part
// (exact, order-preserving). Conv (r10), refine (r9), pool (r5) unchanged.

#define NCODES 16384
#define NELEM  524288   // 8*64*4*16*16
#define NSP    8192     // 8*4*16*16

#define WS_ACCU   0ul
#define WS_HUP    4194304ul
#define WS_REST64 8388608ul
#define WS_PACC   8388608ul    // conv partials [2][NELEM] f64 = 8MB; aliases
                               // rest64(dead after refine)+part(dead after merge)
#define WS_PART   12582912ul   // <=2MB used; refine pbest aliases this
#define WS_ZCL    16777216ul
#define WS_EHF    18874368ul   // emb bf16-hi frags, 2MB
#define WS_ELF    20971520ul   // emb bf16-lo frags, 2MB
#define WS_ESQ    23068672ul
#define WS_TWT    23134208ul
#define WS_IDX    24903680ul
#define WS_CNT    24936448ul
#define WS_FLAGL  25001984ul
#define WS_FLAGC  25034752ul
#define WS_SSE    25034816ul
#define WS_ENT    25034824ul
#define WS_USED   25034832ul
#define WS_RHF    25034848ul   // rest bf16-hi frags, 1MB
#define WS_RLF    26083424ul   // rest bf16-lo frags, 1MB

typedef __attribute__((ext_vector_type(8))) short short8;
typedef __attribute__((ext_vector_type(4))) float floatx4;

struct PBest { double d; int idx; int pad; };

// round-to-nearest-even float -> bf16; also returns hi as float
__device__ inline short bf16rne(float f, float* hi) {
  unsigned u = __float_as_uint(f);
  unsigned r = (u + 0x7FFFu + ((u >> 16) & 1u)) >> 16;
  *hi = __uint_as_float(r << 16);
  return (short)r;
}

// ---------------------------------------------------------------- prep
__global__ __launch_bounds__(256) void prep_kernel(
    const float* __restrict__ z, const float* __restrict__ emb, const float* __restrict__ Wq,
    double* __restrict__ accu, float* __restrict__ zcl,
    short* __restrict__ ehf, short* __restrict__ elf,
    float* __restrict__ esq, float* __restrict__ twt,
    int* __restrict__ counts, int* __restrict__ flagcnt,
    double* sse, double* ent, int* usedcnt)
{
  int i = blockIdx.x * 256 + threadIdx.x;
  if (i < NELEM) { accu[i] = 0.0; return; }
  i -= NELEM;
  if (i < NELEM) {  // z [B,C,T,H,W] -> zcl [B,T,H,W,C]
    int c = i & 63, w = (i >> 6) & 15, h = (i >> 10) & 15, t = (i >> 14) & 3, b = i >> 16;
    zcl[i] = z[(((b * 64 + c) * 4 + t) * 16 + h) * 16 + w];
    return;
  }
  i -= NELEM;
  if (i < NCODES * 64) {  // emb -> bf16 split, MFMA B-frag order
    int j = i >> 6, c = i & 63;
    float v = emb[i];
    float hi; short h = bf16rne(v, &hi);
    float hi2; short l = bf16rne(v - hi, &hi2);
    int jt = j >> 4, nn = j & 15, hf = c >> 5, q = (c >> 3) & 3, ii = c & 7;
    size_t slot = ((size_t)(((jt * 2 + hf) * 64) + q * 16 + nn)) * 8 + ii;
    ehf[slot] = h; elf[slot] = l;
    return;
  }
  i -= NCODES * 64;
  if (i < NCODES) {  // e_sq fp32 (ranking only; refine is fp64)
    float s = 0.f;
    for (int c = 0; c < 64; c++) { float v = emb[i * 64 + c]; s += v * v; }
    esq[i] = s; return;
  }
  i -= NCODES;
  if (i < 442368) {  // twt[qi][tap][ci][co] = Wq[qi][co][ci][tap]
    int qi = i / 110592; int r = i % 110592;
    int tap = r >> 12; int ci = (r >> 6) & 63; int co = r & 63;
    twt[i] = Wq[((qi * 64 + co) * 64 + ci) * 27 + tap];
    return;
  }
  i -= 442368;
  if (i < NCODES) { counts[i] = 0; return; }
  i -= NCODES;
  if (i < 16) {
    if (i < 10) flagcnt[i] = 0;
    else if (i == 10) *sse = 0.0;
    else if (i == 11) *ent = 0.0;
    else if (i == 12) *usedcnt = 0;
  }
}

// ------------------------------------------- pool (area) + frag emit
__global__ __launch_bounds__(256) void pool_kernel(
    const float* __restrict__ zcl, const double* __restrict__ accu,
    double* __restrict__ rest64, short* __restrict__ rhf, short* __restrict__ rlf,
    int N, int tpn, int pn)
{
  __shared__ double psum[4][64];
  int n = blockIdx.x;
  int tid = threadIdx.x;
  int c = tid & 63, ck = tid >> 6;
  if (n >= N) {  // zero pad rows so argmin frags are defined
    if (tid < 64) {
      int pt = n >> 4, m = n & 15, hf = tid >> 5, q = (tid >> 3) & 3, ii = tid & 7;
      size_t slot = ((size_t)(((pt * 2 + hf) * 64) + q * 16 + m)) * 8 + ii;
      rhf[slot] = 0; rlf[slot] = 0;
    }
    return;
  }
  int ppn = pn * pn;
  int b = n / (tpn * ppn); int r = n % (tpn * ppn);
  int u = r / ppn; r %= ppn; int v = r / pn; int x = r % pn;
  int t0 = (u * 4) / tpn, t1 = ((u + 1) * 4 + tpn - 1) / tpn;
  int h0 = (v * 16) / pn, h1 = ((v + 1) * 16 + pn - 1) / pn;
  int w0 = (x * 16) / pn, w1 = ((x + 1) * 16 + pn - 1) / pn;
  int nt = t1 - t0, nh = h1 - h0, nw = w1 - w0;
  int M = nt * nh * nw;
  int chunk = (M + 3) >> 2;
  int m0 = ck * chunk; int m1 = m0 + chunk; if (m1 > M) m1 = M;
  double s = 0.0;
  if (m0 < m1) {
    int tmp = m0 / nw; int wi = m0 - tmp * nw;
    int ti = tmp / nh; int hi = tmp - ti * nh;
    for (int m = m0; m < m1; m++) {
      size_t off = (size_t)((((b * 4 + t0 + ti) * 16 + h0 + hi) * 16 + w0 + wi) * 64 + c);
      s += (double)zcl[off] - accu[off];
      if (++wi == nw) { wi = 0; if (++hi == nh) { hi = 0; ++ti; } }
    }
  }
  psum[ck][c] = s;
  __syncthreads();
  if (tid < 64) {
    double t = ((psum[0][c] + psum[1][c]) + psum[2][c]) + psum[3][c];
    float wt = 1.f / (float)nt, wh = 1.f / (float)nh, ww = 1.f / (float)nw;
    double rv = t * (double)wt * (double)wh * (double)ww;
    rest64[(size_t)n * 64 + c] = rv;
    float rv32 = (float)rv;
    float hi; short h = bf16rne(rv32, &hi);
    float hi2; short l = bf16rne(rv32 - hi, &hi2);
    int pt = n >> 4, m = n & 15, hf = c >> 5, q = (c >> 3) & 3, ii = c & 7;
    size_t slot = ((size_t)(((pt * 2 + hf) * 64) + q * 16 + m)) * 8 + ii;
    rhf[slot] = h; rlf[slot] = l;
  }
}

// ------------------------------------------- argmin pass 1 (bf16 MFMA GEMM)
// grid (NSpad/64, nch): 64 points x (nstripes*128)-code chunk. acc init
// -es/2 (C-input) -> pure max-scan; d=-2a at writeback (exact).
__global__ __launch_bounds__(256) void argmin_kernel(
    const short* __restrict__ rhf, const short* __restrict__ rlf,
    const short* __restrict__ ehf, const short* __restrict__ elf,
    const float* __restrict__ esq, float4* __restrict__ part,
    int NSpad, int nstripes)
{
  __shared__ short8 Ah[4][2][64];
  __shared__ short8 Al[4][2][64];
  __shared__ short8 Bh[8][2][64];
  __shared__ short8 Bl[8][2][64];
  __shared__ float esql[128];
  int tid = threadIdx.x;
  int pbase = blockIdx.x * 64;
  int ch = blockIdx.y;
  {
    const short8* sH = (const short8*)(rhf + (size_t)pbase * 64);
    const short8* sL = (const short8*)(rlf + (size_t)pbase * 64);
    short8* dH = (short8*)Ah; short8* dL = (short8*)Al;
    dH[tid] = sH[tid]; dH[tid + 256] = sH[tid + 256];
    dL[tid] = sL[tid]; dL[tid + 256] = sL[tid + 256];
  }
  __syncthreads();
  int w = tid >> 6, lane = tid & 63, col = lane & 15;
  short8 ah0 = Ah[w][0][lane], ah1 = Ah[w][1][lane];
  short8 al0 = Al[w][0][lane], al1 = Al[w][1][lane];
  float M1[4], M2[4]; int I1[4];
#pragma unroll
  for (int r = 0; r < 4; r++) { M1[r] = -3.4e38f; M2[r] = -3.4e38f; I1[r] = 0x7fffffff; }
  for (int s = 0; s < nstripes; s++) {
    int j0 = ch * (nstripes * 128) + s * 128;
    __syncthreads();
    {
      const short8* sH = (const short8*)(ehf + (size_t)j0 * 64);
      const short8* sL = (const short8*)(elf + (size_t)j0 * 64);
      short8* dH = (short8*)Bh; short8* dL = (short8*)Bl;
#pragma unroll
      for (int it = 0; it < 4; it++) { dH[tid + it * 256] = sH[tid + it * 256]; dL[tid + it * 256] = sL[tid + it * 256]; }
      if (tid < 128) esql[tid] = esq[j0 + tid];
    }
    __syncthreads();
    floatx4 acc[8];
#pragma unroll
    for (int jt = 0; jt < 8; jt++) {
      float c0 = -0.5f * esql[jt * 16 + col];
      acc[jt] = (floatx4){c0, c0, c0, c0};
    }
#pragma unroll
    for (int jt = 0; jt < 8; jt++) {
      short8 bh0 = Bh[jt][0][lane], bl0 = Bl[jt][0][lane];
      short8 bh1 = Bh[jt][1][lane], bl1 = Bl[jt][1][lane];
      acc[jt] = __builtin_amdgcn_mfma_f32_16x16x32_bf16(al0, bh0, acc[jt], 0, 0, 0);
      acc[jt] = __builtin_amdgcn_mfma_f32_16x16x32_bf16(ah0, bl0, acc[jt], 0, 0, 0);
      acc[jt] = __builtin_amdgcn_mfma_f32_16x16x32_bf16(ah0, bh0, acc[jt], 0, 0, 0);
      acc[jt] = __builtin_amdgcn_mfma_f32_16x16x32_bf16(al1, bh1, acc[jt], 0, 0, 0);
      acc[jt] = __builtin_amdgcn_mfma_f32_16x16x32_bf16(ah1, bl1, acc[jt], 0, 0, 0);
      acc[jt] = __builtin_amdgcn_mfma_f32_16x16x32_bf16(ah1, bh1, acc[jt], 0, 0, 0);
    }
#pragma unroll
    for (int jt = 0; jt < 8; jt++) {
      int j = j0 + jt * 16 + col;
#pragma unroll
      for (int r = 0; r < 4; r++) {
        float a = acc[jt][r];   // a = dot - es/2 ; argmax a == argmin d
        if (a > M1[r]) { M2[r] = M1[r]; M1[r] = a; I1[r] = j; }
        else if (a > M2[r]) { M2[r] = a; }
      }
    }
  }
  // top-2(max) merge across the 16 lanes of each quad
#pragma unroll
  for (int off = 1; off < 16; off <<= 1) {
#pragma unroll
    for (int r = 0; r < 4; r++) {
      float o1 = __shfl_xor(M1[r], off);
      int   oi = __shfl_xor(I1[r], off);
      float o2 = __shfl_xor(M2[r], off);
      bool bwin = (o1 > M1[r]) || (o1 == M1[r] && oi < I1[r]);
      float nm2 = bwin ? fmaxf(M1[r], o2) : fmaxf(M2[r], o1);
      if (bwin) { M1[r] = o1; I1[r] = oi; }
      M2[r] = nm2;
    }
  }
  if (col == 0) {
    int quad = lane >> 4;
#pragma unroll
    for (int r = 0; r < 4; r++) {
      int p = pbase + w * 16 + quad * 4 + r;
      part[(size_t)ch * NSpad + p] =
          make_float4(-2.f * M1[r], -2.f * M2[r], __int_as_float(I1[r]), 0.f);
    }
  }
}

// ---------------------------- merge chunks, flag near-ties to global list
__global__ __launch_bounds__(256) void reduce_kernel(
    const float4* __restrict__ part, int* __restrict__ idx_cur,
    float* __restrict__ out_idx, int* flagcnt, int* flaglist,
    int N, int NSpad, int nch)
{
  int n = blockIdx.x * 256 + threadIdx.x;
  if (n >= N) return;
  float m1 = 3.4e38f, m2 = 3.4e38f; int i1 = 0x7fffffff;
  for (int ch = 0; ch < nch; ch++) {
    float4 q = part[(size_t)ch * NSpad + n];
    float o1 = q.x, o2 = q.y; int oi = __float_as_int(q.z);
    bool bwin = (o1 < m1) || (o1 == m1 && oi < i1);
    float nm2 = bwin ? fminf(m1, o2) : fminf(m2, o1);
    if (bwin) { m1 = o1; i1 = oi; }
    m2 = nm2;
  }
  idx_cur[n] = i1;
  out_idx[n] = (float)i1;
  if (m2 - m1 < 0.01f) {
    int pos = atomicAdd(flagcnt, 1);
    flaglist[pos] = n;
  }
}

// -------------------- parallel fp64 rescan: block = (flag, 4096-code chunk)
__global__ __launch_bounds__(256) void refine_kernel(
    const double* __restrict__ rest64, const float* __restrict__ emb,
    const int* __restrict__ flagcnt, const int* __restrict__ flaglist,
    PBest* __restrict__ pbest)
{
  __shared__ double rl[64];
  __shared__ double bm[256];
  __shared__ int    bi[256];
  int f = blockIdx.x;
  if (f >= *flagcnt) return;
  int ch = blockIdx.y;
  int tid = threadIdx.x;
  int n = flaglist[f];
  if (tid < 64) rl[tid] = rest64[(size_t)n * 64 + tid];
  __syncthreads();
  double best = 1e300; int bidx = 0x7fffffff;
#pragma unroll 1
  for (int k = 0; k < 16; k++) {
    int j = ch * 4096 + k * 256 + tid;
    double d = 0.0;
    const float4* ej = (const float4*)&emb[(size_t)j * 64];
#pragma unroll
    for (int c4 = 0; c4 < 16; c4++) {
      float4 ev = ej[c4];
      double d0 = rl[c4 * 4 + 0] - (double)ev.x;
      double d1 = rl[c4 * 4 + 1] - (double)ev.y;
      double d2 = rl[c4 * 4 + 2] - (double)ev.z;
      double d3 = rl[c4 * 4 + 3] - (double)ev.w;
      d += d0 * d0; d += d1 * d1; d += d2 * d2; d += d3 * d3;
    }
    if (d < best) { best = d; bidx = j; }  // ascending j keeps first min
  }
  bm[tid] = best; bi[tid] = bidx;
  __syncthreads();
  for (int s = 128; s > 0; s >>= 1) {
    if (tid < s) {
      double ob = bm[tid + s]; int oi = bi[tid + s];
      if (ob < bm[tid] || (ob == bm[tid] && oi < bi[tid])) { bm[tid] = ob; bi[tid] = oi; }
    }
    __syncthreads();
  }
  if (tid == 0) { pbest[f * 4 + ch].d = bm[0]; pbest[f * 4 + ch].idx = bi[0]; }
}

// -------------------------------- fold 4 chunk results per flagged point
__global__ __launch_bounds__(256) void refine_merge_kernel(
    const PBest* __restrict__ pbest, const int* __restrict__ flagcnt,
    const int* __restrict__ flaglist, int* __restrict__ idx_cur,
    float* __restrict__ out_idx)
{
  int f = blockIdx.x * 256 + threadIdx.x;
  if (f >= *flagcnt) return;
  double best = 1e300; int bidx = 0x7fffffff;
  for (int ch = 0; ch < 4; ch++) {
    double d = pbest[f * 4 + ch].d; int j = pbest[f * 4 + ch].idx;
    if (d < best || (d == best && j < bidx)) { best = d; bidx = j; }
  }
  int n = flaglist[f];
  idx_cur[n] = bidx;
  out_idx[n] = (float)bidx;
}

// ------------------------------------------------------- trilinear upsample
__device__ inline void axis_map(int L, int outlen, int i, int* j0, int* j1, float* a0, float* a1) {
  if (L == 1) { *j0 = 0; *j1 = 0; *a0 = 1.f; *a1 = 0.f; return; }
  double scale = (double)L / (double)outlen;
  double src = (i + 0.5) * scale - 0.5;
  if (src < 0.0) src = 0.0;
  int i0 = (int)floor(src); if (i0 > L - 1) i0 = L - 1;
  int i1 = i0 + 1; if (i1 > L - 1) i1 = L - 1;
  double wv = src - (double)i0;
  if (i0 == i1) {
    float p = (float)(1.0 - wv), q = (float)wv;
    *a0 = p + q; *a1 = 0.f;
  } else { *a0 = (float)(1.0 - wv); *a1 = (float)wv; }
  *j0 = i0; *j1 = i1;
}

__global__ __launch_bounds__(256) void upsample_kernel(
    const float* __restrict__ emb, const int* __restrict__ idx_cur,
    double* __restrict__ hup, int tpn, int pn)
{
  int e = blockIdx.x * 256 + threadIdx.x;
  int c = e & 63, w = (e >> 6) & 15, h = (e >> 10) & 15, t = (e >> 14) & 3, b = e >> 16;
  int t0, t1, h0, h1, w0, w1; float ta0, ta1, ha0, ha1, wa0, wa1;
  axis_map(tpn, 4, t, &t0, &t1, &ta0, &ta1);
  axis_map(pn, 16, h, &h0, &h1, &ha0, &ha1);
  axis_map(pn, 16, w, &w0, &w1, &wa0, &wa1);
  int ti[2] = {t0, t1}; float ta[2] = {ta0, ta1};
  int hi[2] = {h0, h1}; float ha[2] = {ha0, ha1};
  int wi[2] = {w0, w1}; float wa[2] = {wa0, wa1};
  double val = 0.0;
  for (int a = 0; a < 2; a++)
    for (int bb = 0; bb < 2; bb++)
      for (int cc = 0; cc < 2; cc++) {
        double wgt = (double)ta[a] * (double)ha[bb] * (double)wa[cc];
        if (wgt != 0.0) {
          int code = idx_cur[((b * tpn + ti[a]) * pn + hi[bb]) * pn + wi[cc]];
          val += wgt * (double)emb[(size_t)code * 64 + c];
        }
      }
  hup[e] = val;
}

// --------------------- conv3d partial (ci-half) — 2w x 4co per thread
__global__ __launch_bounds__(256) void conv_part_kernel(
    const double* __restrict__ hup, const float* __restrict__ twt,
    double* __restrict__ pacc, int qi)
{
  __shared__ double hl[4][3][4][18];              // [cc][tt][hh][ww]
  __shared__ __align__(16) float wl[27][4][64];   // [tap][cc][co]
  int bid = blockIdx.x;
  int s = bid & 1, hp = (bid >> 1) & 7, t = (bid >> 4) & 3, b = bid >> 6;
  int tid = threadIdx.x;
  int co4 = tid & 15;
  int wp  = (tid >> 4) & 7;
  int th  = tid >> 7;
  int h = hp * 2 + th, w0 = wp * 2;
  double acc0[4] = {0.0, 0.0, 0.0, 0.0};
  double acc1[4] = {0.0, 0.0, 0.0, 0.0};
  for (int ci0 = s * 32; ci0 < s * 32 + 32; ci0 += 4) {
    __syncthreads();
    for (int i = tid; i < 864; i += 256) {
      int ww = i % 18; int r = i / 18;
      int hh = r & 3; r >>= 2; int tt = r % 3; int cc = r / 3;
      int gt = t - 1 + tt, gh = hp * 2 - 1 + hh, gw = ww - 1;
      double v = 0.0;
      if (gt >= 0 && gt < 4 && gh >= 0 && gh < 16 && gw >= 0 && gw < 16)
        v = hup[(size_t)((((b * 4 + gt) * 16 + gh) * 16 + gw) * 64 + ci0 + cc)];
      hl[cc][tt][hh][ww] = v;
    }
    for (int i = tid; i < 6912; i += 256) {
      int co = i & 63; int r = i >> 6; int cc = r & 3; int tap = r >> 2;
      wl[tap][cc][co] = twt[(size_t)(((qi * 27 + tap) * 64 + ci0 + cc) * 64 + co)];
    }
    __syncthreads();
    for (int tap = 0; tap < 27; tap++) {
      int dt = tap / 9, dh = (tap / 3) % 3, dw = tap % 3;
#pragma unroll
      for (int cc = 0; cc < 4; cc++) {
        float4 wf = *(const float4*)&wl[tap][cc][co4 * 4];
        double hva = hl[cc][dt][th + dh][w0 + dw];
        double hvb = hl[cc][dt][th + dh][w0 + 1 + dw];
        double w0d = (double)wf.x, w1d = (double)wf.y, w2d = (double)wf.z, w3d = (double)wf.w;
        acc0[0] += hva * w0d; acc0[1] += hva * w1d; acc0[2] += hva * w2d; acc0[3] += hva * w3d;
        acc1[0] += hvb * w0d; acc1[1] += hvb * w1d; acc1[2] += hvb * w2d; acc1[3] += hvb * w3d;
      }
    }
  }
  size_t e0 = (size_t)((((b * 4 + t) * 16 + h) * 16 + w0) * 64 + co4 * 4);
  double* d0 = &pacc[(size_t)s * NELEM + e0];
#pragma unroll
  for (int q = 0; q < 4; q++) d0[q] = acc0[q];
#pragma unroll
  for (int q = 0; q < 4; q++) d0[64 + q] = acc1[q];
}

// ------------------- combine partials + bias + 0.5/0.5 mix + accu + sse
__global__ __launch_bounds__(256) void conv_combine_kernel(
    const double* __restrict__ pacc, const double* __restrict__ hup,
    const float* __restrict__ bq, const float* __restrict__ zcl,
    double* __restrict__ accu, double* sse, int qi)
{
  __shared__ double red[256];
  int tid = threadIdx.x;
  int e = blockIdx.x * 256 + tid;
  int co = e & 63;
  double cv = (pacc[e] + pacc[(size_t)NELEM + e]) + (double)bq[qi * 64 + co];
  double hu = hup[e];
  double na = accu[e] + 0.5 * hu + 0.5 * cv;
  accu[e] = na;
  double df = na - (double)zcl[e];
  red[tid] = df * df;
  __syncthreads();
  for (int s = 128; s > 0; s >>= 1) { if (tid < s) red[tid] += red[tid + s]; __syncthreads(); }
  if (tid == 0) atomicAdd(sse, red[0]);
}

// ---------------------------------------------------------------- stats
__global__ __launch_bounds__(256) void bincount_kernel(const int* __restrict__ idx_cur, int* counts) {
  int i = blockIdx.x * 256 + threadIdx.x;
  if (i < NSP) atomicAdd(&counts[idx_cur[i]], 1);
}

__global__ __launch_bounds__(256) void stats_kernel(
    const int* __restrict__ counts, float* __restrict__ usage_out, double* ent, int* usedcnt)
{
  __shared__ double re[256];
  __shared__ int ru[256];
  int j = blockIdx.x * 256 + threadIdx.x;
  int cnt = counts[j];
  double p = (double)cnt / 8192.0;
  usage_out[j] = (float)p;
  re[threadIdx.x] = p * log(p + 1e-10);
  ru[threadIdx.x] = cnt > 0 ? 1 : 0;
  __syncthreads();
  for (int s = 128; s > 0; s >>= 1) {
    if (threadIdx.x < s) { re[threadIdx.x] += re[threadIdx.x + s]; ru[threadIdx.x] += ru[threadIdx.x + s]; }
    __syncthreads();
  }
  if (threadIdx.x == 0) { atomicAdd(ent, re[0]); atomicAdd(usedcnt, ru[0]); }
}

__global__ void final_kernel(const double* sse, const double* ent, const int* usedcnt, float* out) {
  if (threadIdx.x == 0) {
    out[NELEM]     = (float)(*sse * 0.25 / 524288.0 / 10.0);
    out[NELEM + 1] = (float)exp(-*ent);
    out[NELEM + 2] = (float)((double)*usedcnt / 16384.0);
  }
}

__global__ __launch_bounds__(256) void embst_kernel(const double* __restrict__ accu, float* __restrict__ out) {
  int e = blockIdx.x * 256 + threadIdx.x;
  int w = e & 15, h = (e >> 4) & 15, t = (e >> 8) & 3, c = (e >> 10) & 63, b = e >> 16;
  out[e] = (float)accu[(size_t)(((((b * 4 + t) * 16 + h) * 16 + w) * 64) + c)];
}

// ---------------------------------------------------------------- launch
extern "C" void kernel_launch(void* const* d_in, const int* in_sizes, int n_in,
                              void* d_out, int out_size, void* d_ws, size_t ws_size,
                              hipStream_t stream) {
  static const int T_PN_h[10] = {1, 1, 2, 2, 2, 4, 4, 4, 4, 4};
  static const int V_PN_h[10] = {1, 2, 3, 4, 5, 6, 8, 10, 13, 16};
  // qi from bit-exact fp64 emulation of np.linspace+argmin (ties: si=2->1, si=7->3)
  static const int QI_h[10]   = {0, 0, 1, 1, 1, 2, 2, 3, 3, 3};
  static const int NS_h[10]   = {8, 32, 144, 256, 400, 1152, 2048, 3200, 5408, 8192};
  static const int OB_h[10]   = {540675, 540683, 540715, 540859, 541115,
                                 541515, 542667, 544715, 547915, 553323};
  // chunks: small scales 64x256 codes (latency), mid 32x512 (balance), big 16x1024
  static const int NCH_h[10]  = {64, 64, 64, 64, 64, 32, 32, 32, 16, 16};

  const float* z   = (const float*)d_in[0];
  const float* emb = (const float*)d_in[1];
  const float* Wq  = (const float*)d_in[2];
  const float* bq  = (const float*)d_in[3];
  float* out = (float*)d_out;
  char* ws = (char*)d_ws;

  double* accu    = (double*)(ws + WS_ACCU);
  double* hup     = (double*)(ws + WS_HUP);
  double* rest64  = (double*)(ws + WS_REST64);
  double* pacc    = (double*)(ws + WS_PACC);
  float4* part    = (float4*)(ws + WS_PART);
  PBest*  pbest   = (PBest*)(ws + WS_PART);
  float*  zcl     = (float*)(ws + WS_ZCL);
  short*  ehf     = (short*)(ws + WS_EHF);
  short*  elf     = (short*)(ws + WS_ELF);
  float*  esq     = (float*)(ws + WS_ESQ);
  float*  twt     = (float*)(ws + WS_TWT);
  int*    idx_cur = (int*)(ws + WS_IDX);
  int*    counts  = (int*)(ws + WS_CNT);
  int*    flaglist= (int*)(ws + WS_FLAGL);
  int*    flagcnt = (int*)(ws + WS_FLAGC);
  double* sse     = (double*)(ws + WS_SSE);
  double* ent     = (double*)(ws + WS_ENT);
  int*    usedcnt = (int*)(ws + WS_USED);
  short*  rhf     = (short*)(ws + WS_RHF);
  short*  rlf     = (short*)(ws + WS_RLF);

  prep_kernel<<<10049, 256, 0, stream>>>(z, emb, Wq, accu, zcl, ehf, elf, esq, twt,
                                         counts, flagcnt, sse, ent, usedcnt);

  for (int si = 0; si < 10; si++) {
    int tpn = T_PN_h[si], pn = V_PN_h[si], N = NS_h[si];
    int NSpad = (N + 63) & ~63;
    int nch = NCH_h[si];
    int nstripes = (NCODES / nch) / 128;
    pool_kernel<<<NSpad, 256, 0, stream>>>(zcl, accu, rest64, rhf, rlf, N, tpn, pn);
    dim3 ag(NSpad / 64, nch);
    argmin_kernel<<<ag, 256, 0, stream>>>(rhf, rlf, ehf, elf, esq, part, NSpad, nstripes);
    reduce_kernel<<<(N + 255) / 256, 256, 0, stream>>>(part, idx_cur, out + OB_h[si],
                                                       flagcnt + si, flaglist, N, NSpad, nch);
    dim3 rg(N, 4);
    refine_kernel<<<rg, 256, 0, stream>>>(rest64, emb, flagcnt + si, flaglist, pbest);
    refine_merge_kernel<<<(N + 255) / 256, 256, 0, stream>>>(pbest, flagcnt + si, flaglist,
                                                             idx_cur, out + OB_h[si]);
    upsample_kernel<<<NELEM / 256, 256, 0, stream>>>(emb, idx_cur, hup, tpn, pn);
    conv_part_kernel<<<512, 256, 0, stream>>>(hup, twt, pacc, QI_h[si]);
    conv_combine_kernel<<<NELEM / 256, 256, 0, stream>>>(pacc, hup, bq, zcl, accu, sse, QI_h[si]);
  }

  bincount_kernel<<<32, 256, 0, stream>>>(idx_cur, counts);
  stats_kernel<<<64, 256, 0, stream>>>(counts, out + 524291, ent, usedcnt);
  final_kernel<<<1, 64, 0, stream>>>(sse, ent, usedcnt, out);
  embst_kernel<<<NELEM / 256, 256, 0, stream>>>(accu, out);
}

// Round 12
// 2290.661 us; speedup vs baseline: 1.9586x; 1.0466x over previous
//
#include <hip/hip_runtime.h>
#include <math.h>

// MultiScaleCodebook on MI355X — round 12: async LDS staging.
// r11 post-mortem: argmin VALUBusy 76% is the *staging* path (load+ds_write
// pairs), not the scan; conv_part likewise spends 27 copy-pairs/thread/chunk
// on weights. Fix: __builtin_amdgcn_global_load_lds width=16 (m97 pattern;
// staging loops are already wave-uniform-base + lane*16B). Math untouched —
// barriers drain vmcnt, so LDS contents are bit-identical to r11.

#define NCODES 16384
#define NELEM  524288   // 8*64*4*16*16
#define NSP    8192     // 8*4*16*16

#define WS_ACCU   0ul
#define WS_HUP    4194304ul
#define WS_REST64 8388608ul
#define WS_PACC   8388608ul    // conv partials [2][NELEM] f64 = 8MB; aliases
                               // rest64(dead after refine)+part(dead after merge)
#define WS_PART   12582912ul   // <=2MB used; refine pbest aliases this
#define WS_ZCL    16777216ul
#define WS_EHF    18874368ul   // emb bf16-hi frags, 2MB
#define WS_ELF    20971520ul   // emb bf16-lo frags, 2MB
#define WS_ESQ    23068672ul
#define WS_TWT    23134208ul
#define WS_IDX    24903680ul
#define WS_CNT    24936448ul
#define WS_FLAGL  25001984ul
#define WS_FLAGC  25034752ul
#define WS_SSE    25034816ul
#define WS_ENT    25034824ul
#define WS_USED   25034832ul
#define WS_RHF    25034848ul   // rest bf16-hi frags, 1MB
#define WS_RLF    26083424ul   // rest bf16-lo frags, 1MB

typedef __attribute__((ext_vector_type(8))) short short8;
typedef __attribute__((ext_vector_type(4))) float floatx4;

struct PBest { double d; int idx; int pad; };

// async 16B global->LDS: lds dest = wave-uniform base + lane*16
__device__ __forceinline__ void gl2lds16(const void* g, void* l) {
  __builtin_amdgcn_global_load_lds(
      (const __attribute__((address_space(1))) unsigned int*)g,
      (__attribute__((address_space(3))) unsigned int*)l, 16, 0, 0);
}

// round-to-nearest-even float -> bf16; also returns hi as float
__device__ inline short bf16rne(float f, float* hi) {
  unsigned u = __float_as_uint(f);
  unsigned r = (u + 0x7FFFu + ((u >> 16) & 1u)) >> 16;
  *hi = __uint_as_float(r << 16);
  return (short)r;
}

// ---------------------------------------------------------------- prep
__global__ __launch_bounds__(256) void prep_kernel(
    const float* __restrict__ z, const float* __restrict__ emb, const float* __restrict__ Wq,
    double* __restrict__ accu, float* __restrict__ zcl,
    short* __restrict__ ehf, short* __restrict__ elf,
    float* __restrict__ esq, float* __restrict__ twt,
    int* __restrict__ counts, int* __restrict__ flagcnt,
    double* sse, double* ent, int* usedcnt)
{
  int i = blockIdx.x * 256 + threadIdx.x;
  if (i < NELEM) { accu[i] = 0.0; return; }
  i -= NELEM;
  if (i < NELEM) {  // z [B,C,T,H,W] -> zcl [B,T,H,W,C]
    int c = i & 63, w = (i >> 6) & 15, h = (i >> 10) & 15, t = (i >> 14) & 3, b = i >> 16;
    zcl[i] = z[(((b * 64 + c) * 4 + t) * 16 + h) * 16 + w];
    return;
  }
  i -= NELEM;
  if (i < NCODES * 64) {  // emb -> bf16 split, MFMA B-frag order
    int j = i >> 6, c = i & 63;
    float v = emb[i];
    float hi; short h = bf16rne(v, &hi);
    float hi2; short l = bf16rne(v - hi, &hi2);
    int jt = j >> 4, nn = j & 15, hf = c >> 5, q = (c >> 3) & 3, ii = c & 7;
    size_t slot = ((size_t)(((jt * 2 + hf) * 64) + q * 16 + nn)) * 8 + ii;
    ehf[slot] = h; elf[slot] = l;
    return;
  }
  i -= NCODES * 64;
  if (i < NCODES) {  // e_sq fp32 (ranking only; refine is fp64)
    float s = 0.f;
    for (int c = 0; c < 64; c++) { float v = emb[i * 64 + c]; s += v * v; }
    esq[i] = s; return;
  }
  i -= NCODES;
  if (i < 442368) {  // twt[qi][tap][ci][co] = Wq[qi][co][ci][tap]
    int qi = i / 110592; int r = i % 110592;
    int tap = r >> 12; int ci = (r >> 6) & 63; int co = r & 63;
    twt[i] = Wq[((qi * 64 + co) * 64 + ci) * 27 + tap];
    return;
  }
  i -= 442368;
  if (i < NCODES) { counts[i] = 0; return; }
  i -= NCODES;
  if (i < 16) {
    if (i < 10) flagcnt[i] = 0;
    else if (i == 10) *sse = 0.0;
    else if (i == 11) *ent = 0.0;
    else if (i == 12) *usedcnt = 0;
  }
}

// ------------------------------------------- pool (area) + frag emit
__global__ __launch_bounds__(256) void pool_kernel(
    const float* __restrict__ zcl, const double* __restrict__ accu,
    double* __restrict__ rest64, short* __restrict__ rhf, short* __restrict__ rlf,
    int N, int tpn, int pn)
{
  __shared__ double psum[4][64];
  int n = blockIdx.x;
  int tid = threadIdx.x;
  int c = tid & 63, ck = tid >> 6;
  if (n >= N) {  // zero pad rows so argmin frags are defined
    if (tid < 64) {
      int pt = n >> 4, m = n & 15, hf = tid >> 5, q = (tid >> 3) & 3, ii = tid & 7;
      size_t slot = ((size_t)(((pt * 2 + hf) * 64) + q * 16 + m)) * 8 + ii;
      rhf[slot] = 0; rlf[slot] = 0;
    }
    return;
  }
  int ppn = pn * pn;
  int b = n / (tpn * ppn); int r = n % (tpn * ppn);
  int u = r / ppn; r %= ppn; int v = r / pn; int x = r % pn;
  int t0 = (u * 4) / tpn, t1 = ((u + 1) * 4 + tpn - 1) / tpn;
  int h0 = (v * 16) / pn, h1 = ((v + 1) * 16 + pn - 1) / pn;
  int w0 = (x * 16) / pn, w1 = ((x + 1) * 16 + pn - 1) / pn;
  int nt = t1 - t0, nh = h1 - h0, nw = w1 - w0;
  int M = nt * nh * nw;
  int chunk = (M + 3) >> 2;
  int m0 = ck * chunk; int m1 = m0 + chunk; if (m1 > M) m1 = M;
  double s = 0.0;
  if (m0 < m1) {
    int tmp = m0 / nw; int wi = m0 - tmp * nw;
    int ti = tmp / nh; int hi = tmp - ti * nh;
    for (int m = m0; m < m1; m++) {
      size_t off = (size_t)((((b * 4 + t0 + ti) * 16 + h0 + hi) * 16 + w0 + wi) * 64 + c);
      s += (double)zcl[off] - accu[off];
      if (++wi == nw) { wi = 0; if (++hi == nh) { hi = 0; ++ti; } }
    }
  }
  psum[ck][c] = s;
  __syncthreads();
  if (tid < 64) {
    double t = ((psum[0][c] + psum[1][c]) + psum[2][c]) + psum[3][c];
    float wt = 1.f / (float)nt, wh = 1.f / (float)nh, ww = 1.f / (float)nw;
    double rv = t * (double)wt * (double)wh * (double)ww;
    rest64[(size_t)n * 64 + c] = rv;
    float rv32 = (float)rv;
    float hi; short h = bf16rne(rv32, &hi);
    float hi2; short l = bf16rne(rv32 - hi, &hi2);
    int pt = n >> 4, m = n & 15, hf = c >> 5, q = (c >> 3) & 3, ii = c & 7;
    size_t slot = ((size_t)(((pt * 2 + hf) * 64) + q * 16 + m)) * 8 + ii;
    rhf[slot] = h; rlf[slot] = l;
  }
}

// ------------------------------------------- argmin pass 1 (bf16 MFMA GEMM)
// grid (NSpad/64, nch): 64 points x (nstripes*128)-code chunk. acc init
// -es/2 -> pure max-scan; d=-2a at writeback. Staging via global_load_lds.
__global__ __launch_bounds__(256) void argmin_kernel(
    const short* __restrict__ rhf, const short* __restrict__ rlf,
    const short* __restrict__ ehf, const short* __restrict__ elf,
    const float* __restrict__ esq, float4* __restrict__ part,
    int NSpad, int nstripes)
{
  __shared__ short8 Ah[4][2][64];
  __shared__ short8 Al[4][2][64];
  __shared__ short8 Bh[8][2][64];
  __shared__ short8 Bl[8][2][64];
  __shared__ float esql[128];
  int tid = threadIdx.x;
  int pbase = blockIdx.x * 64;
  int ch = blockIdx.y;
  int wv64 = tid & ~63, ln = tid & 63;
  {  // A frags: 512 short8 each of H/L — async linear copy
    const short8* sH = (const short8*)(rhf + (size_t)pbase * 64);
    const short8* sL = (const short8*)(rlf + (size_t)pbase * 64);
    short8* dH = (short8*)Ah; short8* dL = (short8*)Al;
#pragma unroll
    for (int it = 0; it < 2; it++) {
      int idx = it * 256 + wv64;
      gl2lds16(sH + idx + ln, dH + idx);
      gl2lds16(sL + idx + ln, dL + idx);
    }
  }
  __syncthreads();
  int w = tid >> 6, lane = tid & 63, col = lane & 15;
  short8 ah0 = Ah[w][0][lane], ah1 = Ah[w][1][lane];
  short8 al0 = Al[w][0][lane], al1 = Al[w][1][lane];
  float M1[4], M2[4]; int I1[4];
#pragma unroll
  for (int r = 0; r < 4; r++) { M1[r] = -3.4e38f; M2[r] = -3.4e38f; I1[r] = 0x7fffffff; }
  for (int s = 0; s < nstripes; s++) {
    int j0 = ch * (nstripes * 128) + s * 128;
    __syncthreads();
    {  // B frags: 1024 short8 each — async linear copy
      const short8* sH = (const short8*)(ehf + (size_t)j0 * 64);
      const short8* sL = (const short8*)(elf + (size_t)j0 * 64);
      short8* dH = (short8*)Bh; short8* dL = (short8*)Bl;
#pragma unroll
      for (int it = 0; it < 4; it++) {
        int idx = it * 256 + wv64;
        gl2lds16(sH + idx + ln, dH + idx);
        gl2lds16(sL + idx + ln, dL + idx);
      }
      if (tid < 128) esql[tid] = esq[j0 + tid];
    }
    __syncthreads();
    floatx4 acc[8];
#pragma unroll
    for (int jt = 0; jt < 8; jt++) {
      float c0 = -0.5f * esql[jt * 16 + col];
      acc[jt] = (floatx4){c0, c0, c0, c0};
    }
#pragma unroll
    for (int jt = 0; jt < 8; jt++) {
      short8 bh0 = Bh[jt][0][lane], bl0 = Bl[jt][0][lane];
      short8 bh1 = Bh[jt][1][lane], bl1 = Bl[jt][1][lane];
      acc[jt] = __builtin_amdgcn_mfma_f32_16x16x32_bf16(al0, bh0, acc[jt], 0, 0, 0);
      acc[jt] = __builtin_amdgcn_mfma_f32_16x16x32_bf16(ah0, bl0, acc[jt], 0, 0, 0);
      acc[jt] = __builtin_amdgcn_mfma_f32_16x16x32_bf16(ah0, bh0, acc[jt], 0, 0, 0);
      acc[jt] = __builtin_amdgcn_mfma_f32_16x16x32_bf16(al1, bh1, acc[jt], 0, 0, 0);
      acc[jt] = __builtin_amdgcn_mfma_f32_16x16x32_bf16(ah1, bl1, acc[jt], 0, 0, 0);
      acc[jt] = __builtin_amdgcn_mfma_f32_16x16x32_bf16(ah1, bh1, acc[jt], 0, 0, 0);
    }
#pragma unroll
    for (int jt = 0; jt < 8; jt++) {
      int j = j0 + jt * 16 + col;
#pragma unroll
      for (int r = 0; r < 4; r++) {
        float a = acc[jt][r];   // a = dot - es/2 ; argmax a == argmin d
        if (a > M1[r]) { M2[r] = M1[r]; M1[r] = a; I1[r] = j; }
        else if (a > M2[r]) { M2[r] = a; }
      }
    }
  }
#pragma unroll
  for (int off = 1; off < 16; off <<= 1) {
#pragma unroll
    for (int r = 0; r < 4; r++) {
      float o1 = __shfl_xor(M1[r], off);
      int   oi = __shfl_xor(I1[r], off);
      float o2 = __shfl_xor(M2[r], off);
      bool bwin = (o1 > M1[r]) || (o1 == M1[r] && oi < I1[r]);
      float nm2 = bwin ? fmaxf(M1[r], o2) : fmaxf(M2[r], o1);
      if (bwin) { M1[r] = o1; I1[r] = oi; }
      M2[r] = nm2;
    }
  }
  if (col == 0) {
    int quad = lane >> 4;
#pragma unroll
    for (int r = 0; r < 4; r++) {
      int p = pbase + w * 16 + quad * 4 + r;
      part[(size_t)ch * NSpad + p] =
          make_float4(-2.f * M1[r], -2.f * M2[r], __int_as_float(I1[r]), 0.f);
    }
  }
}

// ---------------------------- merge chunks, flag near-ties to global list
__global__ __launch_bounds__(256) void reduce_kernel(
    const float4* __restrict__ part, int* __restrict__ idx_cur,
    float* __restrict__ out_idx, int* flagcnt, int* flaglist,
    int N, int NSpad, int nch)
{
  int n = blockIdx.x * 256 + threadIdx.x;
  if (n >= N) return;
  float m1 = 3.4e38f, m2 = 3.4e38f; int i1 = 0x7fffffff;
  for (int ch = 0; ch < nch; ch++) {
    float4 q = part[(size_t)ch * NSpad + n];
    float o1 = q.x, o2 = q.y; int oi = __float_as_int(q.z);
    bool bwin = (o1 < m1) || (o1 == m1 && oi < i1);
    float nm2 = bwin ? fminf(m1, o2) : fminf(m2, o1);
    if (bwin) { m1 = o1; i1 = oi; }
    m2 = nm2;
  }
  idx_cur[n] = i1;
  out_idx[n] = (float)i1;
  if (m2 - m1 < 0.01f) {
    int pos = atomicAdd(flagcnt, 1);
    flaglist[pos] = n;
  }
}

// -------------------- parallel fp64 rescan: block = (flag, 4096-code chunk)
__global__ __launch_bounds__(256) void refine_kernel(
    const double* __restrict__ rest64, const float* __restrict__ emb,
    const int* __restrict__ flagcnt, const int* __restrict__ flaglist,
    PBest* __restrict__ pbest)
{
  __shared__ double rl[64];
  __shared__ double bm[256];
  __shared__ int    bi[256];
  int f = blockIdx.x;
  if (f >= *flagcnt) return;
  int ch = blockIdx.y;
  int tid = threadIdx.x;
  int n = flaglist[f];
  if (tid < 64) rl[tid] = rest64[(size_t)n * 64 + tid];
  __syncthreads();
  double best = 1e300; int bidx = 0x7fffffff;
#pragma unroll 1
  for (int k = 0; k < 16; k++) {
    int j = ch * 4096 + k * 256 + tid;
    double d = 0.0;
    const float4* ej = (const float4*)&emb[(size_t)j * 64];
#pragma unroll
    for (int c4 = 0; c4 < 16; c4++) {
      float4 ev = ej[c4];
      double d0 = rl[c4 * 4 + 0] - (double)ev.x;
      double d1 = rl[c4 * 4 + 1] - (double)ev.y;
      double d2 = rl[c4 * 4 + 2] - (double)ev.z;
      double d3 = rl[c4 * 4 + 3] - (double)ev.w;
      d += d0 * d0; d += d1 * d1; d += d2 * d2; d += d3 * d3;
    }
    if (d < best) { best = d; bidx = j; }  // ascending j keeps first min
  }
  bm[tid] = best; bi[tid] = bidx;
  __syncthreads();
  for (int s = 128; s > 0; s >>= 1) {
    if (tid < s) {
      double ob = bm[tid + s]; int oi = bi[tid + s];
      if (ob < bm[tid] || (ob == bm[tid] && oi < bi[tid])) { bm[tid] = ob; bi[tid] = oi; }
    }
    __syncthreads();
  }
  if (tid == 0) { pbest[f * 4 + ch].d = bm[0]; pbest[f * 4 + ch].idx = bi[0]; }
}

// -------------------------------- fold 4 chunk results per flagged point
__global__ __launch_bounds__(256) void refine_merge_kernel(
    const PBest* __restrict__ pbest, const int* __restrict__ flagcnt,
    const int* __restrict__ flaglist, int* __restrict__ idx_cur,
    float* __restrict__ out_idx)
{
  int f = blockIdx.x * 256 + threadIdx.x;
  if (f >= *flagcnt) return;
  double best = 1e300; int bidx = 0x7fffffff;
  for (int ch = 0; ch < 4; ch++) {
    double d = pbest[f * 4 + ch].d; int j = pbest[f * 4 + ch].idx;
    if (d < best || (d == best && j < bidx)) { best = d; bidx = j; }
  }
  int n = flaglist[f];
  idx_cur[n] = bidx;
  out_idx[n] = (float)bidx;
}

// ------------------------------------------------------- trilinear upsample
__device__ inline void axis_map(int L, int outlen, int i, int* j0, int* j1, float* a0, float* a1) {
  if (L == 1) { *j0 = 0; *j1 = 0; *a0 = 1.f; *a1 = 0.f; return; }
  double scale = (double)L / (double)outlen;
  double src = (i + 0.5) * scale - 0.5;
  if (src < 0.0) src = 0.0;
  int i0 = (int)floor(src); if (i0 > L - 1) i0 = L - 1;
  int i1 = i0 + 1; if (i1 > L - 1) i1 = L - 1;
  double wv = src - (double)i0;
  if (i0 == i1) {
    float p = (float)(1.0 - wv), q = (float)wv;
    *a0 = p + q; *a1 = 0.f;
  } else { *a0 = (float)(1.0 - wv); *a1 = (float)wv; }
  *j0 = i0; *j1 = i1;
}

__global__ __launch_bounds__(256) void upsample_kernel(
    const float* __restrict__ emb, const int* __restrict__ idx_cur,
    double* __restrict__ hup, int tpn, int pn)
{
  int e = blockIdx.x * 256 + threadIdx.x;
  int c = e & 63, w = (e >> 6) & 15, h = (e >> 10) & 15, t = (e >> 14) & 3, b = e >> 16;
  int t0, t1, h0, h1, w0, w1; float ta0, ta1, ha0, ha1, wa0, wa1;
  axis_map(tpn, 4, t, &t0, &t1, &ta0, &ta1);
  axis_map(pn, 16, h, &h0, &h1, &ha0, &ha1);
  axis_map(pn, 16, w, &w0, &w1, &wa0, &wa1);
  int ti[2] = {t0, t1}; float ta[2] = {ta0, ta1};
  int hi[2] = {h0, h1}; float ha[2] = {ha0, ha1};
  int wi[2] = {w0, w1}; float wa[2] = {wa0, wa1};
  double val = 0.0;
  for (int a = 0; a < 2; a++)
    for (int bb = 0; bb < 2; bb++)
      for (int cc = 0; cc < 2; cc++) {
        double wgt = (double)ta[a] * (double)ha[bb] * (double)wa[cc];
        if (wgt != 0.0) {
          int code = idx_cur[((b * tpn + ti[a]) * pn + hi[bb]) * pn + wi[cc]];
          val += wgt * (double)emb[(size_t)code * 64 + c];
        }
      }
  hup[e] = val;
}

// --------------------- conv3d partial (ci-half) — 2w x 4co per thread
// Weights staged async (1728 float4 per ci-chunk, wave-uniform tail guard);
// halo keeps VALU path (per-lane boundary predication).
__global__ __launch_bounds__(256) void conv_part_kernel(
    const double* __restrict__ hup, const float* __restrict__ twt,
    double* __restrict__ pacc, int qi)
{
  __shared__ double hl[4][3][4][18];              // [cc][tt][hh][ww]
  __shared__ __align__(16) float wl[27][4][64];   // [tap][cc][co]
  int bid = blockIdx.x;
  int s = bid & 1, hp = (bid >> 1) & 7, t = (bid >> 4) & 3, b = bid >> 6;
  int tid = threadIdx.x;
  int co4 = tid & 15;
  int wp  = (tid >> 4) & 7;
  int th  = tid >> 7;
  int h = hp * 2 + th, w0 = wp * 2;
  int wv64 = tid & ~63, ln = tid & 63;
  double acc0[4] = {0.0, 0.0, 0.0, 0.0};
  double acc1[4] = {0.0, 0.0, 0.0, 0.0};
  for (int ci0 = s * 32; ci0 < s * 32 + 32; ci0 += 4) {
    __syncthreads();
    for (int i = tid; i < 864; i += 256) {
      int ww = i % 18; int r = i / 18;
      int hh = r & 3; r >>= 2; int tt = r % 3; int cc = r / 3;
      int gt = t - 1 + tt, gh = hp * 2 - 1 + hh, gw = ww - 1;
      double v = 0.0;
      if (gt >= 0 && gt < 4 && gh >= 0 && gh < 16 && gw >= 0 && gw < 16)
        v = hup[(size_t)((((b * 4 + gt) * 16 + gh) * 16 + gw) * 64 + ci0 + cc)];
      hl[cc][tt][hh][ww] = v;
    }
    {  // weights: 1728 float4 async; tail wave-uniform (1728 = 6*256 + 192)
      const float4* srcb = (const float4*)twt;
      float4* dstb = (float4*)wl;
#pragma unroll
      for (int k = 0; k < 7; k++) {
        int idx = k * 256 + wv64;
        if (idx < 1728) {
          int i2 = idx + ln;
          int tc = i2 >> 4;                  // tap*4+cc
          int tap = tc >> 2, cc = tc & 3, f4 = i2 & 15;
          const float4* g = srcb + ((size_t)((qi * 27 + tap) * 64 + ci0 + cc) * 16 + f4);
          gl2lds16(g, dstb + idx);
        }
      }
    }
    __syncthreads();
    for (int tap = 0; tap < 27; tap++) {
      int dt = tap / 9, dh = (tap / 3) % 3, dw = tap % 3;
#pragma unroll
      for (int cc = 0; cc < 4; cc++) {
        float4 wf = *(const float4*)&wl[tap][cc][co4 * 4];
        double hva = hl[cc][dt][th + dh][w0 + dw];
        double hvb = hl[cc][dt][th + dh][w0 + 1 + dw];
        double w0d = (double)wf.x, w1d = (double)wf.y, w2d = (double)wf.z, w3d = (double)wf.w;
        acc0[0] += hva * w0d; acc0[1] += hva * w1d; acc0[2] += hva * w2d; acc0[3] += hva * w3d;
        acc1[0] += hvb * w0d; acc1[1] += hvb * w1d; acc1[2] += hvb * w2d; acc1[3] += hvb * w3d;
      }
    }
  }
  size_t e0 = (size_t)((((b * 4 + t) * 16 + h) * 16 + w0) * 64 + co4 * 4);
  double* d0 = &pacc[(size_t)s * NELEM + e0];
#pragma unroll
  for (int q = 0; q < 4; q++) d0[q] = acc0[q];
#pragma unroll
  for (int q = 0; q < 4; q++) d0[64 + q] = acc1[q];
}

// ------------------- combine partials + bias + 0.5/0.5 mix + accu + sse
__global__ __launch_bounds__(256) void conv_combine_kernel(
    const double* __restrict__ pacc, const double* __restrict__ hup,
    const float* __restrict__ bq, const float* __restrict__ zcl,
    double* __restrict__ accu, double* sse, int qi)
{
  __shared__ double red[256];
  int tid = threadIdx.x;
  int e = blockIdx.x * 256 + tid;
  int co = e & 63;
  double cv = (pacc[e] + pacc[(size_t)NELEM + e]) + (double)bq[qi * 64 + co];
  double hu = hup[e];
  double na = accu[e] + 0.5 * hu + 0.5 * cv;
  accu[e] = na;
  double df = na - (double)zcl[e];
  red[tid] = df * df;
  __syncthreads();
  for (int s = 128; s > 0; s >>= 1) { if (tid < s) red[tid] += red[tid + s]; __syncthreads(); }
  if (tid == 0) atomicAdd(sse, red[0]);
}

// ---------------------------------------------------------------- stats
__global__ __launch_bounds__(256) void bincount_kernel(const int* __restrict__ idx_cur, int* counts) {
  int i = blockIdx.x * 256 + threadIdx.x;
  if (i < NSP) atomicAdd(&counts[idx_cur[i]], 1);
}

__global__ __launch_bounds__(256) void stats_kernel(
    const int* __restrict__ counts, float* __restrict__ usage_out, double* ent, int* usedcnt)
{
  __shared__ double re[256];
  __shared__ int ru[256];
  int j = blockIdx.x * 256 + threadIdx.x;
  int cnt = counts[j];
  double p = (double)cnt / 8192.0;
  usage_out[j] = (float)p;
  re[threadIdx.x] = p * log(p + 1e-10);
  ru[threadIdx.x] = cnt > 0 ? 1 : 0;
  __syncthreads();
  for (int s = 128; s > 0; s >>= 1) {
    if (threadIdx.x < s) { re[threadIdx.x] += re[threadIdx.x + s]; ru[threadIdx.x] += ru[threadIdx.x + s]; }
    __syncthreads();
  }
  if (threadIdx.x == 0) { atomicAdd(ent, re[0]); atomicAdd(usedcnt, ru[0]); }
}

__global__ void final_kernel(const double* sse, const double* ent, const int* usedcnt, float* out) {
  if (threadIdx.x == 0) {
    out[NELEM]     = (float)(*sse * 0.25 / 524288.0 / 10.0);
    out[NELEM + 1] = (float)exp(-*ent);
    out[NELEM + 2] = (float)((double)*usedcnt / 16384.0);
  }
}

__global__ __launch_bounds__(256) void embst_kernel(const double* __restrict__ accu, float* __restrict__ out) {
  int e = blockIdx.x * 256 + threadIdx.x;
  int w = e & 15, h = (e >> 4) & 15, t = (e >> 8) & 3, c = (e >> 10) & 63, b = e >> 16;
  out[e] = (float)accu[(size_t)(((((b * 4 + t) * 16 + h) * 16 + w) * 64) + c)];
}

// ---------------------------------------------------------------- launch
extern "C" void kernel_launch(void* const* d_in, const int* in_sizes, int n_in,
                              void* d_out, int out_size, void* d_ws, size_t ws_size,
                              hipStream_t stream) {
  static const int T_PN_h[10] = {1, 1, 2, 2, 2, 4, 4, 4, 4, 4};
  static const int V_PN_h[10] = {1, 2, 3, 4, 5, 6, 8, 10, 13, 16};
  // qi from bit-exact fp64 emulation of np.linspace+argmin (ties: si=2->1, si=7->3)
  static const int QI_h[10]   = {0, 0, 1, 1, 1, 2, 2, 3, 3, 3};
  static const int NS_h[10]   = {8, 32, 144, 256, 400, 1152, 2048, 3200, 5408, 8192};
  static const int OB_h[10]   = {540675, 540683, 540715, 540859, 541115,
                                 541515, 542667, 544715, 547915, 553323};
  static const int NCH_h[10]  = {64, 64, 64, 64, 64, 32, 32, 32, 16, 16};

  const float* z   = (const float*)d_in[0];
  const float* emb = (const float*)d_in[1];
  const float* Wq  = (const float*)d_in[2];
  const float* bq  = (const float*)d_in[3];
  float* out = (float*)d_out;
  char* ws = (char*)d_ws;

  double* accu    = (double*)(ws + WS_ACCU);
  double* hup     = (double*)(ws + WS_HUP);
  double* rest64  = (double*)(ws + WS_REST64);
  double* pacc    = (double*)(ws + WS_PACC);
  float4* part    = (float4*)(ws + WS_PART);
  PBest*  pbest   = (PBest*)(ws + WS_PART);
  float*  zcl     = (float*)(ws + WS_ZCL);
  short*  ehf     = (short*)(ws + WS_EHF);
  short*  elf     = (short*)(ws + WS_ELF);
  float*  esq     = (float*)(ws + WS_ESQ);
  float*  twt     = (float*)(ws + WS_TWT);
  int*    idx_cur = (int*)(ws + WS_IDX);
  int*    counts  = (int*)(ws + WS_CNT);
  int*    flaglist= (int*)(ws + WS_FLAGL);
  int*    flagcnt = (int*)(ws + WS_FLAGC);
  double* sse     = (double*)(ws + WS_SSE);
  double* ent     = (double*)(ws + WS_ENT);
  int*    usedcnt = (int*)(ws + WS_USED);
  short*  rhf     = (short*)(ws + WS_RHF);
  short*  rlf     = (short*)(ws + WS_RLF);

  prep_kernel<<<10049, 256, 0, stream>>>(z, emb, Wq, accu, zcl, ehf, elf, esq, twt,
                                         counts, flagcnt, sse, ent, usedcnt);

  for (int si = 0; si < 10; si++) {
    int tpn = T_PN_h[si], pn = V_PN_h[si], N = NS_h[si];
    int NSpad = (N + 63) & ~63;
    int nch = NCH_h[si];
    int nstripes = (NCODES / nch) / 128;
    pool_kernel<<<NSpad, 256, 0, stream>>>(zcl, accu, rest64, rhf, rlf, N, tpn, pn);
    dim3 ag(NSpad / 64, nch);
    argmin_kernel<<<ag, 256, 0, stream>>>(rhf, rlf, ehf, elf, esq, part, NSpad, nstripes);
    reduce_kernel<<<(N + 255) / 256, 256, 0, stream>>>(part, idx_cur, out + OB_h[si],
                                                       flagcnt + si, flaglist, N, NSpad, nch);
    dim3 rg(N, 4);
    refine_kernel<<<rg, 256, 0, stream>>>(rest64, emb, flagcnt + si, flaglist, pbest);
    refine_merge_kernel<<<(N + 255) / 256, 256, 0, stream>>>(pbest, flagcnt + si, flaglist,
                                                             idx_cur, out + OB_h[si]);
    upsample_kernel<<<NELEM / 256, 256, 0, stream>>>(emb, idx_cur, hup, tpn, pn);
    conv_part_kernel<<<512, 256, 0, stream>>>(hup, twt, pacc, QI_h[si]);
    conv_combine_kernel<<<NELEM / 256, 256, 0, stream>>>(pacc, hup, bq, zcl, accu, sse, QI_h[si]);
  }

  bincount_kernel<<<32, 256, 0, stream>>>(idx_cur, counts);
  stats_kernel<<<64, 256, 0, stream>>>(counts, out + 524291, ent, usedcnt);
  final_kernel<<<1, 64, 0, stream>>>(sse, ent, usedcnt, out);
  embst_kernel<<<NELEM / 256, 256, 0, stream>>>(accu, out);
}

// Round 14
// 2275.380 us; speedup vs baseline: 1.9718x; 1.0067x over previous
//
#include <hip/hip_runtime.h>
#include <math.h>

// MultiScaleCodebook on MI355X — round 14: device-scope conv atomics.
// r13 post-mortem: unsafeAtomicAdd f64 is NOT device-scope; the two
// ci-quarter blocks adding the same pacc address can sit on different XCDs,
// whose L2s are not coherent -> lost updates on some launches -> post-timing
// ms_idx divergence. Fix: __hip_atomic_fetch_add(..., AGENT scope) — atomic
// serializes at the device coherence point; two commutative adds/address
// => bit-deterministic result. All r13 perf structure kept (2 B/FMA conv,
// med3 scan, adaptive chunks, async staging).

#define NCODES 16384
#define NELEM  524288   // 8*64*4*16*16
#define NSP    8192     // 8*4*16*16

#define WS_ACCU   0ul
#define WS_HUP    4194304ul
#define WS_REST64 8388608ul
#define WS_PACC   8388608ul    // conv partials [2][NELEM] f64 = 8MB; aliases
                               // rest64(dead after refine)+part(dead after merge)
#define WS_PART   12582912ul   // <=2MB used; refine pbest aliases this
#define WS_ZCL    16777216ul
#define WS_EHF    18874368ul   // emb bf16-hi frags, 2MB
#define WS_ELF    20971520ul   // emb bf16-lo frags, 2MB
#define WS_ESQ    23068672ul
#define WS_TWT    23134208ul
#define WS_IDX    24903680ul
#define WS_CNT    24936448ul
#define WS_FLAGL  25001984ul
#define WS_FLAGC  25034752ul
#define WS_SSE    25034816ul
#define WS_ENT    25034824ul
#define WS_USED   25034832ul
#define WS_RHF    25034848ul   // rest bf16-hi frags, 1MB
#define WS_RLF    26083424ul   // rest bf16-lo frags, 1MB

typedef __attribute__((ext_vector_type(8))) short short8;
typedef __attribute__((ext_vector_type(4))) float floatx4;

struct PBest { double d; int idx; int pad; };

// async 16B global->LDS: lds dest = wave-uniform base + lane*16
__device__ __forceinline__ void gl2lds16(const void* g, void* l) {
  __builtin_amdgcn_global_load_lds(
      (const __attribute__((address_space(1))) unsigned int*)g,
      (__attribute__((address_space(3))) unsigned int*)l, 16, 0, 0);
}

// round-to-nearest-even float -> bf16; also returns hi as float
__device__ inline short bf16rne(float f, float* hi) {
  unsigned u = __float_as_uint(f);
  unsigned r = (u + 0x7FFFu + ((u >> 16) & 1u)) >> 16;
  *hi = __uint_as_float(r << 16);
  return (short)r;
}

// ---------------------------------------------------------------- prep
__global__ __launch_bounds__(256) void prep_kernel(
    const float* __restrict__ z, const float* __restrict__ emb, const float* __restrict__ Wq,
    double* __restrict__ accu, float* __restrict__ zcl,
    short* __restrict__ ehf, short* __restrict__ elf,
    float* __restrict__ esq, float* __restrict__ twt,
    int* __restrict__ counts, int* __restrict__ flagcnt,
    double* sse, double* ent, int* usedcnt)
{
  int i = blockIdx.x * 256 + threadIdx.x;
  if (i < NELEM) { accu[i] = 0.0; return; }
  i -= NELEM;
  if (i < NELEM) {  // z [B,C,T,H,W] -> zcl [B,T,H,W,C]
    int c = i & 63, w = (i >> 6) & 15, h = (i >> 10) & 15, t = (i >> 14) & 3, b = i >> 16;
    zcl[i] = z[(((b * 64 + c) * 4 + t) * 16 + h) * 16 + w];
    return;
  }
  i -= NELEM;
  if (i < NCODES * 64) {  // emb -> bf16 split, MFMA B-frag order
    int j = i >> 6, c = i & 63;
    float v = emb[i];
    float hi; short h = bf16rne(v, &hi);
    float hi2; short l = bf16rne(v - hi, &hi2);
    int jt = j >> 4, nn = j & 15, hf = c >> 5, q = (c >> 3) & 3, ii = c & 7;
    size_t slot = ((size_t)(((jt * 2 + hf) * 64) + q * 16 + nn)) * 8 + ii;
    ehf[slot] = h; elf[slot] = l;
    return;
  }
  i -= NCODES * 64;
  if (i < NCODES) {  // e_sq fp32 (ranking only; refine is fp64)
    float s = 0.f;
    for (int c = 0; c < 64; c++) { float v = emb[i * 64 + c]; s += v * v; }
    esq[i] = s; return;
  }
  i -= NCODES;
  if (i < 442368) {  // twt[qi][tap][ci][co] = Wq[qi][co][ci][tap]
    int qi = i / 110592; int r = i % 110592;
    int tap = r >> 12; int ci = (r >> 6) & 63; int co = r & 63;
    twt[i] = Wq[((qi * 64 + co) * 64 + ci) * 27 + tap];
    return;
  }
  i -= 442368;
  if (i < NCODES) { counts[i] = 0; return; }
  i -= NCODES;
  if (i < 16) {
    if (i < 10) flagcnt[i] = 0;
    else if (i == 10) *sse = 0.0;
    else if (i == 11) *ent = 0.0;
    else if (i == 12) *usedcnt = 0;
  }
}

// ------------------------------------------- pool (area) + frag emit
__global__ __launch_bounds__(256) void pool_kernel(
    const float* __restrict__ zcl, const double* __restrict__ accu,
    double* __restrict__ rest64, short* __restrict__ rhf, short* __restrict__ rlf,
    int N, int tpn, int pn)
{
  __shared__ double psum[4][64];
  int n = blockIdx.x;
  int tid = threadIdx.x;
  int c = tid & 63, ck = tid >> 6;
  if (n >= N) {  // zero pad rows so argmin frags are defined
    if (tid < 64) {
      int pt = n >> 4, m = n & 15, hf = tid >> 5, q = (tid >> 3) & 3, ii = tid & 7;
      size_t slot = ((size_t)(((pt * 2 + hf) * 64) + q * 16 + m)) * 8 + ii;
      rhf[slot] = 0; rlf[slot] = 0;
    }
    return;
  }
  int ppn = pn * pn;
  int b = n / (tpn * ppn); int r = n % (tpn * ppn);
  int u = r / ppn; r %= ppn; int v = r / pn; int x = r % pn;
  int t0 = (u * 4) / tpn, t1 = ((u + 1) * 4 + tpn - 1) / tpn;
  int h0 = (v * 16) / pn, h1 = ((v + 1) * 16 + pn - 1) / pn;
  int w0 = (x * 16) / pn, w1 = ((x + 1) * 16 + pn - 1) / pn;
  int nt = t1 - t0, nh = h1 - h0, nw = w1 - w0;
  int M = nt * nh * nw;
  int chunk = (M + 3) >> 2;
  int m0 = ck * chunk; int m1 = m0 + chunk; if (m1 > M) m1 = M;
  double s = 0.0;
  if (m0 < m1) {
    int tmp = m0 / nw; int wi = m0 - tmp * nw;
    int ti = tmp / nh; int hi = tmp - ti * nh;
    for (int m = m0; m < m1; m++) {
      size_t off = (size_t)((((b * 4 + t0 + ti) * 16 + h0 + hi) * 16 + w0 + wi) * 64 + c);
      s += (double)zcl[off] - accu[off];
      if (++wi == nw) { wi = 0; if (++hi == nh) { hi = 0; ++ti; } }
    }
  }
  psum[ck][c] = s;
  __syncthreads();
  if (tid < 64) {
    double t = ((psum[0][c] + psum[1][c]) + psum[2][c]) + psum[3][c];
    float wt = 1.f / (float)nt, wh = 1.f / (float)nh, ww = 1.f / (float)nw;
    double rv = t * (double)wt * (double)wh * (double)ww;
    rest64[(size_t)n * 64 + c] = rv;
    float rv32 = (float)rv;
    float hi; short h = bf16rne(rv32, &hi);
    float hi2; short l = bf16rne(rv32 - hi, &hi2);
    int pt = n >> 4, m = n & 15, hf = c >> 5, q = (c >> 3) & 3, ii = c & 7;
    size_t slot = ((size_t)(((pt * 2 + hf) * 64) + q * 16 + m)) * 8 + ii;
    rhf[slot] = h; rlf[slot] = l;
  }
}

// ------------------------------------------- argmin pass 1 (bf16 MFMA GEMM)
__global__ __launch_bounds__(256) void argmin_kernel(
    const short* __restrict__ rhf, const short* __restrict__ rlf,
    const short* __restrict__ ehf, const short* __restrict__ elf,
    const float* __restrict__ esq, float4* __restrict__ part,
    int NSpad, int nstripes)
{
  __shared__ short8 Ah[4][2][64];
  __shared__ short8 Al[4][2][64];
  __shared__ short8 Bh[8][2][64];
  __shared__ short8 Bl[8][2][64];
  __shared__ float esql[128];
  int tid = threadIdx.x;
  int pbase = blockIdx.x * 64;
  int ch = blockIdx.y;
  int wv64 = tid & ~63, ln = tid & 63;
  {  // A frags: async linear copy
    const short8* sH = (const short8*)(rhf + (size_t)pbase * 64);
    const short8* sL = (const short8*)(rlf + (size_t)pbase * 64);
    short8* dH = (short8*)Ah; short8* dL = (short8*)Al;
#pragma unroll
    for (int it = 0; it < 2; it++) {
      int idx = it * 256 + wv64;
      gl2lds16(sH + idx + ln, dH + idx);
      gl2lds16(sL + idx + ln, dL + idx);
    }
  }
  __syncthreads();
  int w = tid >> 6, lane = tid & 63, col = lane & 15;
  short8 ah0 = Ah[w][0][lane], ah1 = Ah[w][1][lane];
  short8 al0 = Al[w][0][lane], al1 = Al[w][1][lane];
  float M1[4], M2[4]; int I1[4];
#pragma unroll
  for (int r = 0; r < 4; r++) { M1[r] = -3.4e38f; M2[r] = -3.4e38f; I1[r] = 0x7fffffff; }
  for (int s = 0; s < nstripes; s++) {
    int j0 = ch * (nstripes * 128) + s * 128;
    __syncthreads();
    {  // B frags: async linear copy
      const short8* sH = (const short8*)(ehf + (size_t)j0 * 64);
      const short8* sL = (const short8*)(elf + (size_t)j0 * 64);
      short8* dH = (short8*)Bh; short8* dL = (short8*)Bl;
#pragma unroll
      for (int it = 0; it < 4; it++) {
        int idx = it * 256 + wv64;
        gl2lds16(sH + idx + ln, dH + idx);
        gl2lds16(sL + idx + ln, dL + idx);
      }
      if (tid < 128) esql[tid] = esq[j0 + tid];
    }
    __syncthreads();
    floatx4 acc[8];
#pragma unroll
    for (int jt = 0; jt < 8; jt++) {
      float c0 = -0.5f * esql[jt * 16 + col];
      acc[jt] = (floatx4){c0, c0, c0, c0};
    }
#pragma unroll
    for (int jt = 0; jt < 8; jt++) {
      short8 bh0 = Bh[jt][0][lane], bl0 = Bl[jt][0][lane];
      short8 bh1 = Bh[jt][1][lane], bl1 = Bl[jt][1][lane];
      acc[jt] = __builtin_amdgcn_mfma_f32_16x16x32_bf16(al0, bh0, acc[jt], 0, 0, 0);
      acc[jt] = __builtin_amdgcn_mfma_f32_16x16x32_bf16(ah0, bl0, acc[jt], 0, 0, 0);
      acc[jt] = __builtin_amdgcn_mfma_f32_16x16x32_bf16(ah0, bh0, acc[jt], 0, 0, 0);
      acc[jt] = __builtin_amdgcn_mfma_f32_16x16x32_bf16(al1, bh1, acc[jt], 0, 0, 0);
      acc[jt] = __builtin_amdgcn_mfma_f32_16x16x32_bf16(ah1, bl1, acc[jt], 0, 0, 0);
      acc[jt] = __builtin_amdgcn_mfma_f32_16x16x32_bf16(ah1, bh1, acc[jt], 0, 0, 0);
    }
#pragma unroll
    for (int jt = 0; jt < 8; jt++) {
      int j = j0 + jt * 16 + col;
#pragma unroll
      for (int r = 0; r < 4; r++) {
        float a = acc[jt][r];   // a = dot - es/2 ; argmax a == argmin d
        float nm2 = fmaxf(fminf(a, M1[r]), M2[r]);
        bool c = a > M1[r];
        M1[r] = fmaxf(a, M1[r]);
        I1[r] = c ? j : I1[r];
        M2[r] = nm2;
      }
    }
  }
#pragma unroll
  for (int off = 1; off < 16; off <<= 1) {
#pragma unroll
    for (int r = 0; r < 4; r++) {
      float o1 = __shfl_xor(M1[r], off);
      int   oi = __shfl_xor(I1[r], off);
      float o2 = __shfl_xor(M2[r], off);
      bool bwin = (o1 > M1[r]) || (o1 == M1[r] && oi < I1[r]);
      float nm2 = bwin ? fmaxf(M1[r], o2) : fmaxf(M2[r], o1);
      if (bwin) { M1[r] = o1; I1[r] = oi; }
      M2[r] = nm2;
    }
  }
  if (col == 0) {
    int quad = lane >> 4;
#pragma unroll
    for (int r = 0; r < 4; r++) {
      int p = pbase + w * 16 + quad * 4 + r;
      part[(size_t)ch * NSpad + p] =
          make_float4(-2.f * M1[r], -2.f * M2[r], __int_as_float(I1[r]), 0.f);
    }
  }
}

// ---------------------------- merge chunks, flag near-ties to global list
__global__ __launch_bounds__(256) void reduce_kernel(
    const float4* __restrict__ part, int* __restrict__ idx_cur,
    float* __restrict__ out_idx, int* flagcnt, int* flaglist,
    int N, int NSpad, int nch)
{
  int n = blockIdx.x * 256 + threadIdx.x;
  if (n >= N) return;
  float m1 = 3.4e38f, m2 = 3.4e38f; int i1 = 0x7fffffff;
  for (int ch = 0; ch < nch; ch++) {
    float4 q = part[(size_t)ch * NSpad + n];
    float o1 = q.x, o2 = q.y; int oi = __float_as_int(q.z);
    bool bwin = (o1 < m1) || (o1 == m1 && oi < i1);
    float nm2 = bwin ? fminf(m1, o2) : fminf(m2, o1);
    if (bwin) { m1 = o1; i1 = oi; }
    m2 = nm2;
  }
  idx_cur[n] = i1;
  out_idx[n] = (float)i1;
  if (m2 - m1 < 0.01f) {
    int pos = atomicAdd(flagcnt, 1);
    flaglist[pos] = n;
  }
}

// -------------------- parallel fp64 rescan: block = (flag, 4096-code chunk)
__global__ __launch_bounds__(256) void refine_kernel(
    const double* __restrict__ rest64, const float* __restrict__ emb,
    const int* __restrict__ flagcnt, const int* __restrict__ flaglist,
    PBest* __restrict__ pbest)
{
  __shared__ double rl[64];
  __shared__ double bm[256];
  __shared__ int    bi[256];
  int f = blockIdx.x;
  if (f >= *flagcnt) return;
  int ch = blockIdx.y;
  int tid = threadIdx.x;
  int n = flaglist[f];
  if (tid < 64) rl[tid] = rest64[(size_t)n * 64 + tid];
  __syncthreads();
  double best = 1e300; int bidx = 0x7fffffff;
#pragma unroll 1
  for (int k = 0; k < 16; k++) {
    int j = ch * 4096 + k * 256 + tid;
    double d = 0.0;
    const float4* ej = (const float4*)&emb[(size_t)j * 64];
#pragma unroll
    for (int c4 = 0; c4 < 16; c4++) {
      float4 ev = ej[c4];
      double d0 = rl[c4 * 4 + 0] - (double)ev.x;
      double d1 = rl[c4 * 4 + 1] - (double)ev.y;
      double d2 = rl[c4 * 4 + 2] - (double)ev.z;
      double d3 = rl[c4 * 4 + 3] - (double)ev.w;
      d += d0 * d0; d += d1 * d1; d += d2 * d2; d += d3 * d3;
    }
    if (d < best) { best = d; bidx = j; }  // ascending j keeps first min
  }
  bm[tid] = best; bi[tid] = bidx;
  __syncthreads();
  for (int s = 128; s > 0; s >>= 1) {
    if (tid < s) {
      double ob = bm[tid + s]; int oi = bi[tid + s];
      if (ob < bm[tid] || (ob == bm[tid] && oi < bi[tid])) { bm[tid] = ob; bi[tid] = oi; }
    }
    __syncthreads();
  }
  if (tid == 0) { pbest[f * 4 + ch].d = bm[0]; pbest[f * 4 + ch].idx = bi[0]; }
}

// -------------------------------- fold 4 chunk results per flagged point
__global__ __launch_bounds__(256) void refine_merge_kernel(
    const PBest* __restrict__ pbest, const int* __restrict__ flagcnt,
    const int* __restrict__ flaglist, int* __restrict__ idx_cur,
    float* __restrict__ out_idx)
{
  int f = blockIdx.x * 256 + threadIdx.x;
  if (f >= *flagcnt) return;
  double best = 1e300; int bidx = 0x7fffffff;
  for (int ch = 0; ch < 4; ch++) {
    double d = pbest[f * 4 + ch].d; int j = pbest[f * 4 + ch].idx;
    if (d < best || (d == best && j < bidx)) { best = d; bidx = j; }
  }
  int n = flaglist[f];
  idx_cur[n] = bidx;
  out_idx[n] = (float)bidx;
}

// ------------------------- trilinear upsample (+ zero pacc for conv atomics)
__device__ inline void axis_map(int L, int outlen, int i, int* j0, int* j1, float* a0, float* a1) {
  if (L == 1) { *j0 = 0; *j1 = 0; *a0 = 1.f; *a1 = 0.f; return; }
  double scale = (double)L / (double)outlen;
  double src = (i + 0.5) * scale - 0.5;
  if (src < 0.0) src = 0.0;
  int i0 = (int)floor(src); if (i0 > L - 1) i0 = L - 1;
  int i1 = i0 + 1; if (i1 > L - 1) i1 = L - 1;
  double wv = src - (double)i0;
  if (i0 == i1) {
    float p = (float)(1.0 - wv), q = (float)wv;
    *a0 = p + q; *a1 = 0.f;
  } else { *a0 = (float)(1.0 - wv); *a1 = (float)wv; }
  *j0 = i0; *j1 = i1;
}

__global__ __launch_bounds__(256) void upsample_kernel(
    const float* __restrict__ emb, const int* __restrict__ idx_cur,
    double* __restrict__ hup, double* __restrict__ pacc, int tpn, int pn)
{
  int e = blockIdx.x * 256 + threadIdx.x;
  pacc[e] = 0.0; pacc[(size_t)NELEM + e] = 0.0;  // rest64/part dead here
  int c = e & 63, w = (e >> 6) & 15, h = (e >> 10) & 15, t = (e >> 14) & 3, b = e >> 16;
  int t0, t1, h0, h1, w0, w1; float ta0, ta1, ha0, ha1, wa0, wa1;
  axis_map(tpn, 4, t, &t0, &t1, &ta0, &ta1);
  axis_map(pn, 16, h, &h0, &h1, &ha0, &ha1);
  axis_map(pn, 16, w, &w0, &w1, &wa0, &wa1);
  int ti[2] = {t0, t1}; float ta[2] = {ta0, ta1};
  int hi[2] = {h0, h1}; float ha[2] = {ha0, ha1};
  int wi[2] = {w0, w1}; float wa[2] = {wa0, wa1};
  double val = 0.0;
  for (int a = 0; a < 2; a++)
    for (int bb = 0; bb < 2; bb++)
      for (int cc = 0; cc < 2; cc++) {
        double wgt = (double)ta[a] * (double)ha[bb] * (double)wa[cc];
        if (wgt != 0.0) {
          int code = idx_cur[((b * tpn + ti[a]) * pn + hi[bb]) * pn + wi[cc]];
          val += wgt * (double)emb[(size_t)code * 64 + c];
        }
      }
  hup[e] = val;
}

// --------------------- conv3d partial (ci-quarter) — 4w x 4co per thread
// grid 512: bid = [b:3][t:2][hq:2][s:2]; block 256 = th4 x wq4 x co4(16).
// 2 B/FMA LDS. Pairwise DEVICE-SCOPE f64 atomic adds (s0+s1 -> slot0,
// s2+s3 -> slot1): serialized at the device coherence point (cross-XCD
// safe); two commutative adds per address => bit-deterministic.
__global__ __launch_bounds__(256) void conv_part_kernel(
    const double* __restrict__ hup, const float* __restrict__ twt,
    double* __restrict__ pacc, int qi)
{
  __shared__ double hl[4][3][6][18];              // [cc][tt][hh][ww] 10368B
  __shared__ __align__(16) float wl[27][4][64];   // [tap][cc][co] 27648B
  int bid = blockIdx.x;
  int s = bid & 3, hq = (bid >> 2) & 3, t = (bid >> 4) & 3, b = bid >> 6;
  int tid = threadIdx.x;
  int co4 = tid & 15;        // co = co4*4
  int wq  = (tid >> 4) & 3;  // w0 = wq*4
  int th  = tid >> 6;        // h = hq*4 + th
  int h = hq * 4 + th, w0 = wq * 4;
  int wv64 = tid & ~63, ln = tid & 63;
  double acc[4][4];
#pragma unroll
  for (int wi = 0; wi < 4; wi++)
#pragma unroll
    for (int q = 0; q < 4; q++) acc[wi][q] = 0.0;
#pragma unroll 1
  for (int c4i = 0; c4i < 4; c4i++) {
    int ci0 = s * 16 + c4i * 4;
    __syncthreads();
    // halo: 4cc x 3tt x 6hh x 18ww = 1296 (cc fastest for 32B segments)
    for (int i = tid; i < 1296; i += 256) {
      int cc = i & 3; int j = i >> 2;
      int ww = j % 18; int k = j / 18;
      int hh = k % 6, tt = k / 6;
      int gt = t - 1 + tt, gh = hq * 4 - 1 + hh, gw = ww - 1;
      double v = 0.0;
      if (gt >= 0 && gt < 4 && gh >= 0 && gh < 16 && gw >= 0 && gw < 16)
        v = hup[(size_t)((((b * 4 + gt) * 16 + gh) * 16 + gw) * 64 + ci0 + cc)];
      hl[cc][tt][hh][ww] = v;
    }
    {  // weights: 1728 float4 async; tail wave-uniform (1728 = 6*256 + 192)
      const float4* srcb = (const float4*)twt;
      float4* dstb = (float4*)wl;
#pragma unroll
      for (int k = 0; k < 7; k++) {
        int idx = k * 256 + wv64;
        if (idx < 1728) {
          int i2 = idx + ln;
          int tc = i2 >> 4;                  // tap*4+cc
          int tap = tc >> 2, cc = tc & 3, f4 = i2 & 15;
          const float4* g = srcb + ((size_t)((qi * 27 + tap) * 64 + ci0 + cc) * 16 + f4);
          gl2lds16(g, dstb + idx);
        }
      }
    }
    __syncthreads();
#pragma unroll 1
    for (int dtdh = 0; dtdh < 9; dtdh++) {
      int dt = dtdh / 3, dh = dtdh % 3;
#pragma unroll
      for (int cc = 0; cc < 4; cc++) {
        double hv[6];
#pragma unroll
        for (int k = 0; k < 6; k++) hv[k] = hl[cc][dt][th + dh][w0 + k];
#pragma unroll
        for (int dw = 0; dw < 3; dw++) {
          float4 wf = *(const float4*)&wl[dtdh * 3 + dw][cc][co4 * 4];
          double w0d = (double)wf.x, w1d = (double)wf.y, w2d = (double)wf.z, w3d = (double)wf.w;
#pragma unroll
          for (int wi = 0; wi < 4; wi++) {
            double hvv = hv[wi + dw];
            acc[wi][0] += hvv * w0d; acc[wi][1] += hvv * w1d;
            acc[wi][2] += hvv * w2d; acc[wi][3] += hvv * w3d;
          }
        }
      }
    }
  }
  int slot = s >> 1;
  double* base = &pacc[(size_t)slot * NELEM +
                       (size_t)((((b * 4 + t) * 16 + h) * 16 + w0) * 64 + co4 * 4)];
#pragma unroll
  for (int wi = 0; wi < 4; wi++)
#pragma unroll
    for (int q = 0; q < 4; q++)
      __hip_atomic_fetch_add(base + wi * 64 + q, acc[wi][q],
                             __ATOMIC_RELAXED, __HIP_MEMORY_SCOPE_AGENT);
}

// ------------------- combine partials + bias + 0.5/0.5 mix + accu + sse
__global__ __launch_bounds__(256) void conv_combine_kernel(
    const double* __restrict__ pacc, const double* __restrict__ hup,
    const float* __restrict__ bq, const float* __restrict__ zcl,
    double* __restrict__ accu, double* sse, int qi)
{
  __shared__ double red[256];
  int tid = threadIdx.x;
  int e = blockIdx.x * 256 + tid;
  int co = e & 63;
  double cv = (pacc[e] + pacc[(size_t)NELEM + e]) + (double)bq[qi * 64 + co];
  double hu = hup[e];
  double na = accu[e] + 0.5 * hu + 0.5 * cv;
  accu[e] = na;
  double df = na - (double)zcl[e];
  red[tid] = df * df;
  __syncthreads();
  for (int s = 128; s > 0; s >>= 1) { if (tid < s) red[tid] += red[tid + s]; __syncthreads(); }
  if (tid == 0) atomicAdd(sse, red[0]);
}

// ---------------------------------------------------------------- stats
__global__ __launch_bounds__(256) void bincount_kernel(const int* __restrict__ idx_cur, int* counts) {
  int i = blockIdx.x * 256 + threadIdx.x;
  if (i < NSP) atomicAdd(&counts[idx_cur[i]], 1);
}

__global__ __launch_bounds__(256) void stats_kernel(
    const int* __restrict__ counts, float* __restrict__ usage_out, double* ent, int* usedcnt)
{
  __shared__ double re[256];
  __shared__ int ru[256];
  int j = blockIdx.x * 256 + threadIdx.x;
  int cnt = counts[j];
  double p = (double)cnt / 8192.0;
  usage_out[j] = (float)p;
  re[threadIdx.x] = p * log(p + 1e-10);
  ru[threadIdx.x] = cnt > 0 ? 1 : 0;
  __syncthreads();
  for (int s = 128; s > 0; s >>= 1) {
    if (threadIdx.x < s) { re[threadIdx.x] += re[threadIdx.x + s]; ru[threadIdx.x] += ru[threadIdx.x + s]; }
    __syncthreads();
  }
  if (threadIdx.x == 0) { atomicAdd(ent, re[0]); atomicAdd(usedcnt, ru[0]); }
}

__global__ void final_kernel(const double* sse, const double* ent, const int* usedcnt, float* out) {
  if (threadIdx.x == 0) {
    out[NELEM]     = (float)(*sse * 0.25 / 524288.0 / 10.0);
    out[NELEM + 1] = (float)exp(-*ent);
    out[NELEM + 2] = (float)((double)*usedcnt / 16384.0);
  }
}

__global__ __launch_bounds__(256) void embst_kernel(const double* __restrict__ accu, float* __restrict__ out) {
  int e = blockIdx.x * 256 + threadIdx.x;
  int w = e & 15, h = (e >> 4) & 15, t = (e >> 8) & 3, c = (e >> 10) & 63, b = e >> 16;
  out[e] = (float)accu[(size_t)(((((b * 4 + t) * 16 + h) * 16 + w) * 64) + c)];
}

// ---------------------------------------------------------------- launch
extern "C" void kernel_launch(void* const* d_in, const int* in_sizes, int n_in,
                              void* d_out, int out_size, void* d_ws, size_t ws_size,
                              hipStream_t stream) {
  static const int T_PN_h[10] = {1, 1, 2, 2, 2, 4, 4, 4, 4, 4};
  static const int V_PN_h[10] = {1, 2, 3, 4, 5, 6, 8, 10, 13, 16};
  // qi from bit-exact fp64 emulation of np.linspace+argmin (ties: si=2->1, si=7->3)
  static const int QI_h[10]   = {0, 0, 1, 1, 1, 2, 2, 3, 3, 3};
  static const int NS_h[10]   = {8, 32, 144, 256, 400, 1152, 2048, 3200, 5408, 8192};
  static const int OB_h[10]   = {540675, 540683, 540715, 540859, 541115,
                                 541515, 542667, 544715, 547915, 553323};
  static const int NCH_h[10]  = {64, 64, 64, 64, 64, 32, 32, 32, 16, 16};

  const float* z   = (const float*)d_in[0];
  const float* emb = (const float*)d_in[1];
  const float* Wq  = (const float*)d_in[2];
  const float* bq  = (const float*)d_in[3];
  float* out = (float*)d_out;
  char* ws = (char*)d_ws;

  double* accu    = (double*)(ws + WS_ACCU);
  double* hup     = (double*)(ws + WS_HUP);
  double* rest64  = (double*)(ws + WS_REST64);
  double* pacc    = (double*)(ws + WS_PACC);
  float4* part    = (float4*)(ws + WS_PART);
  PBest*  pbest   = (PBest*)(ws + WS_PART);
  float*  zcl     = (float*)(ws + WS_ZCL);
  short*  ehf     = (short*)(ws + WS_EHF);
  short*  elf     = (short*)(ws + WS_ELF);
  float*  esq     = (float*)(ws + WS_ESQ);
  float*  twt     = (float*)(ws + WS_TWT);
  int*    idx_cur = (int*)(ws + WS_IDX);
  int*    counts  = (int*)(ws + WS_CNT);
  int*    flaglist= (int*)(ws + WS_FLAGL);
  int*    flagcnt = (int*)(ws + WS_FLAGC);
  double* sse     = (double*)(ws + WS_SSE);
  double* ent     = (double*)(ws + WS_ENT);
  int*    usedcnt = (int*)(ws + WS_USED);
  short*  rhf     = (short*)(ws + WS_RHF);
  short*  rlf     = (short*)(ws + WS_RLF);

  prep_kernel<<<10049, 256, 0, stream>>>(z, emb, Wq, accu, zcl, ehf, elf, esq, twt,
                                         counts, flagcnt, sse, ent, usedcnt);

  for (int si = 0; si < 10; si++) {
    int tpn = T_PN_h[si], pn = V_PN_h[si], N = NS_h[si];
    int NSpad = (N + 63) & ~63;
    int nch = NCH_h[si];
    int nstripes = (NCODES / nch) / 128;
    pool_kernel<<<NSpad, 256, 0, stream>>>(zcl, accu, rest64, rhf, rlf, N, tpn, pn);
    dim3 ag(NSpad / 64, nch);
    argmin_kernel<<<ag, 256, 0, stream>>>(rhf, rlf, ehf, elf, esq, part, NSpad, nstripes);
    reduce_kernel<<<(N + 255) / 256, 256, 0, stream>>>(part, idx_cur, out + OB_h[si],
                                                       flagcnt + si, flaglist, N, NSpad, nch);
    dim3 rg(N, 4);
    refine_kernel<<<rg, 256, 0, stream>>>(rest64, emb, flagcnt + si, flaglist, pbest);
    refine_merge_kernel<<<(N + 255) / 256, 256, 0, stream>>>(pbest, flagcnt + si, flaglist,
                                                             idx_cur, out + OB_h[si]);
    upsample_kernel<<<NELEM / 256, 256, 0, stream>>>(emb, idx_cur, hup, pacc, tpn, pn);
    conv_part_kernel<<<512, 256, 0, stream>>>(hup, twt, pacc, QI_h[si]);
    conv_combine_kernel<<<NELEM / 256, 256, 0, stream>>>(pacc, hup, bq, zcl, accu, sse, QI_h[si]);
  }

  bincount_kernel<<<32, 256, 0, stream>>>(idx_cur, counts);
  stats_kernel<<<64, 256, 0, stream>>>(counts, out + 524291, ent, usedcnt);
  final_kernel<<<1, 64, 0, stream>>>(sse, ent, usedcnt, out);
  embst_kernel<<<NELEM / 256, 256, 0, stream>>>(accu, out);
}